// Round 2
// baseline (435.880 us; speedup 1.0000x reference)
//
#include <hip/hip_runtime.h>
#include <hip/hip_bf16.h>
#include <math.h>

// BiMambaEncoderLayer: B=2, L=2048, D_MODEL=512, ED=1024, N=16, DCONV=4,
// DT_RANK=32, D_FF=1024. f32 in/out.
// Round-17:
//  (a) bgemm2 (64x128, padded LDS, reg-staged) -> bgemm3 (128xBN, BK=32,
//      global_load_lds width-16 into linear LDS, m97 structure). Flip-dir
//      handled on the per-lane GLOBAL address (LDS dest stays linear).
//  (b) G6 dir0+dir1 fused into ONE dispatch via concat-K (K=2048, shared
//      fw2 panel): out = ffh_f@fw2 + ffh_b@fw2 + 2*fb2 + m_f + m_b.
//  (c) scan6 -> scan7: exploit A_n = (n+1)*A_0 (A_log = log(1..16)) to
//      replace 128 exps/thread with 8 exps + 120 muls. Runtime-checked
//      (uniform branch) with generic fallback, so correctness never
//      depends on input values.
// 11 dispatches, 46 MiB workspace.

#define BD 2
#define LD 2048
#define DMODEL 512
#define EDIM 1024
#define NST 16
#define DTR 32
#define DFF 1024
#define MROWS (BD*LD)   // 4096

typedef __hip_bfloat16 bf16;
typedef __bf16 bf16x8 __attribute__((ext_vector_type(8)));
typedef float  f32x4  __attribute__((ext_vector_type(4)));

__device__ __forceinline__ float sig_(float x) { return 1.f / (1.f + __expf(-x)); }

// async 16B global->LDS (wave-uniform LDS base, per-lane global addr)
__device__ __forceinline__ void glds16(const void* g, void* l)
{
    __builtin_amdgcn_global_load_lds(
        (const __attribute__((address_space(1))) void*)g,
        (__attribute__((address_space(3))) void*)l, 16, 0, 0);
}

// ---------------- prep: all weight transposes + x->bf16, one dispatch --------
__global__ __launch_bounds__(256)
void prep_k(const float* __restrict__ x, bf16* __restrict__ xbf,
            const float* __restrict__ inw_f, const float* __restrict__ inw_b,
            bf16* __restrict__ inwT,
            const float* __restrict__ outw_f, const float* __restrict__ outw_b,
            bf16* __restrict__ outwT,
            const float* __restrict__ fw1, bf16* __restrict__ fw1T,
            const float* __restrict__ fw2, bf16* __restrict__ fw2T)
{
    const int bid = blockIdx.x, tid = threadIdx.x;
    if (bid < 2048) {
        size_t i = (size_t)bid * 1024 + tid * 4;
        float4 v = *(const float4*)(x + i);
        bf16* o = xbf + i;
        o[0] = __float2bfloat16(v.x); o[1] = __float2bfloat16(v.y);
        o[2] = __float2bfloat16(v.z); o[3] = __float2bfloat16(v.w);
        return;
    }
    const float* W; bf16* WT; int R, C, cx, ry;
    if (bid < 4096) {
        int d = (bid - 2048) >> 10, t = (bid - 2048) & 1023;
        W = d ? inw_b : inw_f; WT = inwT + (size_t)d * 2048 * 512;
        R = 512; C = 2048; cx = t & 63; ry = t >> 6;
    } else if (bid < 5120) {
        int d = (bid - 4096) >> 9, t = (bid - 4096) & 511;
        W = d ? outw_b : outw_f; WT = outwT + (size_t)d * 512 * 1024;
        R = 1024; C = 512; cx = t & 15; ry = t >> 4;
    } else if (bid < 5632) {
        int t = bid - 5120; W = fw1; WT = fw1T; R = 512; C = 1024;
        cx = t & 31; ry = t >> 5;
    } else {
        int t = bid - 5632; W = fw2; WT = fw2T; R = 1024; C = 512;
        cx = t & 15; ry = t >> 4;
    }
    __shared__ float tt[32][33];
    const int c0 = cx * 32, r0 = ry * 32;
    const int col = tid & 31, rr = tid >> 5;
#pragma unroll
    for (int p = 0; p < 4; ++p)
        tt[p * 8 + rr][col] = W[(size_t)(r0 + p * 8 + rr) * C + c0 + col];
    __syncthreads();
#pragma unroll
    for (int p = 0; p < 4; ++p)
        WT[(size_t)(c0 + p * 8 + rr) * R + r0 + col] =
            __float2bfloat16(tt[col][p * 8 + rr]);
}

// ---------------- bgemm3: 128xBN MFMA GEMM with global_load_lds --------------
// A[M][lda] bf16 (per-dir Astr; FLIPD1 row-flips dir1; CATK: A half0 at A,
// half1 at A+Astr, K=2*KH, B col = k % KH). BT[N][ldb] bf16 (per-dir Bstr).
// MODE: 0 plain bf16 out; 2 relu+bias bf16; 5 f32 out = v + 2*bias + mp[idx]
// + mp[mpStr+idx] (the fused G6).
template<int BN, int MODE, bool FLIPD1, bool CATK>
__global__ __launch_bounds__(256)
void bgemm3_k(const bf16* __restrict__ A, size_t Astr, int lda,
              const bf16* __restrict__ BT, size_t Bstr, int ldb,
              const float* __restrict__ bias,
              bf16* __restrict__ Cb, size_t Cstr, int ldc,
              const bf16* __restrict__ mp, size_t mpStr,
              float* __restrict__ outp, int K)
{
    constexpr int BM = 128;
    constexpr int FRm = 4, FRn = BN / 32;
    constexpr int KH = DFF;   // concat-K half length (1024)
    __shared__ __align__(16) bf16 As[BM][32];
    __shared__ __align__(16) bf16 Bs[BN][32];
    const int tid = threadIdx.x;
    const int dir = blockIdx.z;
    const bool flip = FLIPD1 && (dir == 1);
    const bf16* Ad = A + (CATK ? (size_t)0 : (size_t)dir * Astr);
    const bf16* Bd = BT + (size_t)dir * Bstr;
    const int bm = blockIdx.y * BM, bn = blockIdx.x * BN;
    const int wave = tid >> 6, lane = tid & 63;
    const int wm = (wave >> 1) * 64, wn = (wave & 1) * (BN / 2);
    const int lm = lane & 15, lq = lane >> 4;
    const int lrow = lane >> 2, lcol = (lane & 3) * 8;
    f32x4 acc[FRm][FRn] = {};

    for (int k0 = 0; k0 < K; k0 += 32) {
        const bf16* Ab = Ad;
        int ka = k0;
        if (CATK && k0 >= KH) { Ab = A + Astr; ka = k0 - KH; }
        const int kb = CATK ? (k0 & (KH - 1)) : k0;
        // stage A tile (128x32 bf16 = 8KB): 2 chunks x 4 waves x 1KB
#pragma unroll
        for (int c = 0; c < 2; ++c) {
            int row = c * 64 + wave * 16 + lrow;
            int gm = bm + row;
            if (flip) gm = (gm & ~(LD - 1)) + (LD - 1 - (gm & (LD - 1)));
            glds16(Ab + (size_t)gm * lda + ka + lcol,
                   &As[c * 64 + wave * 16][0]);
        }
        // stage B tile (BNx32 bf16): BN/64 chunks x 4 waves x 1KB
#pragma unroll
        for (int c = 0; c < BN / 64; ++c) {
            int row = c * 64 + wave * 16 + lrow;
            glds16(Bd + (size_t)(bn + row) * ldb + kb + lcol,
                   &Bs[c * 64 + wave * 16][0]);
        }
        __syncthreads();   // drains vmcnt -> staging complete

        bf16x8 af[FRm], bfr[FRn];
#pragma unroll
        for (int i = 0; i < FRm; ++i)
            af[i] = *(const bf16x8*)&As[wm + 16 * i + lm][lq * 8];
#pragma unroll
        for (int j = 0; j < FRn; ++j)
            bfr[j] = *(const bf16x8*)&Bs[wn + 16 * j + lm][lq * 8];
#pragma unroll
        for (int i = 0; i < FRm; ++i)
#pragma unroll
            for (int j = 0; j < FRn; ++j)
                acc[i][j] = __builtin_amdgcn_mfma_f32_16x16x32_bf16(
                    af[i], bfr[j], acc[i][j], 0, 0, 0);
        __syncthreads();
    }

    bf16* Cd = (MODE == 5) ? nullptr : Cb + (size_t)dir * Cstr;
#pragma unroll
    for (int i = 0; i < FRm; ++i) {
#pragma unroll
        for (int j = 0; j < FRn; ++j) {
            int col = bn + wn + 16 * j + lm;
            float bv = (MODE == 2) ? bias[col]
                     : (MODE == 5) ? 2.f * bias[col] : 0.f;
#pragma unroll
            for (int r = 0; r < 4; ++r) {
                int row = bm + wm + 16 * i + lq * 4 + r;
                float v = acc[i][j][r] + bv;
                size_t idx = (size_t)row * ldc + col;
                if (MODE == 0)      Cd[idx] = __float2bfloat16(v);
                else if (MODE == 2) Cd[idx] = __float2bfloat16(fmaxf(v, 0.f));
                else {
                    float m2 = __bfloat162float(mp[idx])
                             + __bfloat162float(mp[mpStr + idx]);
                    outp[idx] = v + m2;
                }
            }
        }
    }
}

// ---------------- zgate: yrow = silu(x(flip?) @ inw_z) * y2t^T ---------------
__global__ __launch_bounds__(256)
void zgate_k(const bf16* __restrict__ xbf, const bf16* __restrict__ inwT,
             const bf16* __restrict__ y2t_all, bf16* __restrict__ yrow_all)
{
    __shared__ __align__(16) bf16 As[64][40];
    __shared__ __align__(16) bf16 Bs[128][40];
    __shared__ __bf16 sy[64][130];
    const int tid = threadIdx.x;
    const int dir = blockIdx.z;
    const bf16* Bd = inwT + (size_t)dir * (2048 * 512) + (size_t)1024 * 512;
    const bf16* y2t = y2t_all + (size_t)dir * ((size_t)MROWS * EDIM);
    bf16* yrow = yrow_all + (size_t)dir * ((size_t)MROWS * EDIM);
    const int bm = blockIdx.y * 64, bn = blockIdx.x * 128;
    const int wave = tid >> 6, lane = tid & 63;
    const int wm = (wave >> 1) * 32, wn = (wave & 1) * 64;
    const int lm = lane & 15, lq = lane >> 4;
    f32x4 acc[2][4] = {};

    for (int k0 = 0; k0 < 512; k0 += 32) {
        {
            int row = tid >> 2, col = (tid & 3) * 8;
            int gm = bm + row;
            if (dir == 1) gm = (gm & ~(LD - 1)) + (LD - 1 - (gm & (LD - 1)));
            *(bf16x8*)&As[row][col] =
                *(const bf16x8*)(xbf + (size_t)gm * 512 + k0 + col);
        }
#pragma unroll
        for (int p = 0; p < 2; ++p) {
            int row = p * 64 + (tid >> 2), col = (tid & 3) * 8;
            *(bf16x8*)&Bs[row][col] =
                *(const bf16x8*)(Bd + (size_t)(bn + row) * 512 + k0 + col);
        }
        __syncthreads();
        bf16x8 af[2], bfr[4];
#pragma unroll
        for (int i = 0; i < 2; ++i)
            af[i] = *(const bf16x8*)&As[wm + 16 * i + lm][lq * 8];
#pragma unroll
        for (int j = 0; j < 4; ++j)
            bfr[j] = *(const bf16x8*)&Bs[wn + 16 * j + lm][lq * 8];
#pragma unroll
        for (int i = 0; i < 2; ++i)
#pragma unroll
            for (int j = 0; j < 4; ++j)
                acc[i][j] = __builtin_amdgcn_mfma_f32_16x16x32_bf16(
                    af[i], bfr[j], acc[i][j], 0, 0, 0);
        __syncthreads();
    }

    {
        const int b = bm >> 11, l0 = bm & (LD - 1);
        int e = tid >> 1, lh = (tid & 1) * 32;
        const bf16* yp = y2t + ((size_t)b * EDIM + bn + e) * LD + l0 + lh;
#pragma unroll
        for (int i = 0; i < 4; ++i) {
            bf16x8 v = *(const bf16x8*)(yp + i * 8);
#pragma unroll
            for (int j = 0; j < 8; ++j) sy[lh + i * 8 + j][e] = v[j];
        }
    }
    __syncthreads();
#pragma unroll
    for (int i = 0; i < 2; ++i) {
#pragma unroll
        for (int j = 0; j < 4; ++j) {
            int col = bn + wn + 16 * j + lm;
#pragma unroll
            for (int r = 0; r < 4; ++r) {
                int row = bm + wm + 16 * i + lq * 4 + r;
                float z = acc[i][j][r];
                float g = z * sig_(z);
                float y = (float)sy[(row - bm)][col - bn];
                yrow[(size_t)row * EDIM + col] = __float2bfloat16(g * y);
            }
        }
    }
}

// ---------------- conv(4)+bias+silu+transpose, dir-merged --------------------
__global__ __launch_bounds__(256)
void conv2_k(const bf16* __restrict__ xs2,
             const float* __restrict__ cw_f, const float* __restrict__ cb_f,
             const float* __restrict__ cw_b, const float* __restrict__ cb_b,
             bf16* __restrict__ xct2)
{
    __shared__ float sxs[67][64];
    __shared__ float sout[64][65];
    const int tid = threadIdx.x;
    const int dir = blockIdx.z;
    const bf16* xs = xs2 + (size_t)dir * ((size_t)MROWS * EDIM);
    const float* w  = dir ? cw_b : cw_f;
    const float* cb = dir ? cb_b : cb_f;
    bf16* xct = xct2 + (size_t)dir * ((size_t)MROWS * EDIM);
    const int e0 = blockIdx.x * 64;
    const int bl0 = blockIdx.y * 64;
    const int lloc0 = bl0 & (LD - 1);
    const int b = bl0 >> 11;
    {
        int row4 = tid >> 6, col = tid & 63;
#pragma unroll
        for (int i = 0; i < 17; ++i) {
            int hr = i * 4 + row4;
            if (hr < 67) {
                int lr = lloc0 + hr - 3;
                sxs[hr][col] = (lr >= 0)
                    ? __bfloat162float(xs[(size_t)(bl0 + hr - 3) * EDIM + e0 + col]) : 0.f;
            }
        }
    }
    __syncthreads();
    {
        int lr4 = tid >> 6, e = tid & 63;
        float w0 = w[(e0 + e) * 4 + 0], w1 = w[(e0 + e) * 4 + 1];
        float w2 = w[(e0 + e) * 4 + 2], w3 = w[(e0 + e) * 4 + 3];
        float cbv = cb[e0 + e];
#pragma unroll
        for (int i = 0; i < 16; ++i) {
            int lr = i * 4 + lr4;
            float acc = cbv;
            acc = fmaf(sxs[lr + 0][e], w0, acc);
            acc = fmaf(sxs[lr + 1][e], w1, acc);
            acc = fmaf(sxs[lr + 2][e], w2, acc);
            acc = fmaf(sxs[lr + 3][e], w3, acc);
            sout[e][lr] = acc * sig_(acc);
        }
    }
    __syncthreads();
    {
        int er4 = tid >> 6, l = tid & 63;
#pragma unroll
        for (int i = 0; i < 16; ++i) {
            int er = i * 4 + er4;
            xct[((size_t)b * EDIM + e0 + er) * LD + lloc0 + l] =
                __float2bfloat16(sout[er][l]);
        }
    }
}

// ---------------- G2 dir-merged: dbl_t = (xc^T @ xproj)^T --------------------
__global__ __launch_bounds__(256)
void g2_k(const bf16* __restrict__ xct2, const float* __restrict__ xp_f,
          const float* __restrict__ xp_b, float* __restrict__ dblt2)
{
    __shared__ __align__(16) float As[32][18];
    __shared__ __align__(16) float Bs[32][66];
    const int tid = threadIdx.x;
    const int dir = blockIdx.y;
    const bf16* xct = xct2 + (size_t)dir * ((size_t)MROWS * EDIM);
    const float* xproj = dir ? xp_b : xp_f;
    float* dblt = dblt2 + (size_t)dir * (2 * 64 * LD);
    const int r0 = blockIdx.x * 16;
    const int bB = r0 >> 11, l0 = r0 & (LD - 1);
    const int row = tid >> 4, col4 = (tid & 15) * 4;
    float acc[4] = {};

    for (int k0 = 0; k0 < EDIM; k0 += 32) {
        {
            int k = tid >> 3, ls = (tid & 7) * 2;
            const bf16* p = xct + ((size_t)bB * EDIM + k0 + k) * LD + l0 + ls;
            As[k][ls] = __bfloat162float(p[0]);
            As[k][ls + 1] = __bfloat162float(p[1]);
        }
        {
            int k = tid >> 3, ns = (tid & 7) * 8;
            const float* p = xproj + (size_t)(k0 + k) * 64 + ns;
            float4 v0 = *(const float4*)p, v1 = *(const float4*)(p + 4);
            float* d = &Bs[k][ns];
            d[0]=v0.x; d[1]=v0.y; d[2]=v0.z; d[3]=v0.w;
            d[4]=v1.x; d[5]=v1.y; d[6]=v1.z; d[7]=v1.w;
        }
        __syncthreads();
#pragma unroll
        for (int kk = 0; kk < 32; ++kk) {
            float a = As[kk][row];
            float4 b4 = *(const float4*)&Bs[kk][col4];
            acc[0] = fmaf(a, b4.x, acc[0]);
            acc[1] = fmaf(a, b4.y, acc[1]);
            acc[2] = fmaf(a, b4.z, acc[2]);
            acc[3] = fmaf(a, b4.w, acc[3]);
        }
        __syncthreads();
    }
#pragma unroll
    for (int j = 0; j < 4; ++j)
        dblt[((size_t)bB * 64 + col4 + j) * LD + l0 + row] = acc[j];
}

// ---------------- G3 dir-merged: dlt_t(bf16) = softplus(...)^T ---------------
__global__ __launch_bounds__(256)
void g3_k(const float* __restrict__ dblt2,
          const float* __restrict__ dtw_f, const float* __restrict__ dtb_f,
          const float* __restrict__ dtw_b, const float* __restrict__ dtb_b,
          bf16* __restrict__ dltt2)
{
    __shared__ __align__(16) float As[16][68];
    __shared__ __align__(16) float Bs[16][68];
    const int tid = threadIdx.x;
    const int dir = blockIdx.z;
    const float* Ap = dblt2 + (size_t)dir * (2 * 64 * LD);
    const float* Bw = dir ? dtw_b : dtw_f;
    const float* bias = dir ? dtb_b : dtb_f;
    bf16* Ct = dltt2 + (size_t)dir * ((size_t)MROWS * EDIM);
    const int bm = blockIdx.y * 64;
    const int bn = blockIdx.x * 64;
    const int bB = bm >> 11, l0 = bm & (LD - 1);
    const int tx = tid & 15, ty = tid >> 4;
    float acc[4][4] = {};

    for (int k0 = 0; k0 < DTR; k0 += 16) {
#pragma unroll
        for (int i = 0; i < 4; ++i) {
            int k = i * 4 + (tid >> 6), ll = tid & 63;
            As[k][ll] = Ap[((size_t)bB * 64 + k0 + k) * LD + l0 + ll];
        }
#pragma unroll
        for (int i = 0; i < 4; ++i) {
            int idx = tid + 256 * i;
            int nl = idx & 63, kl = idx >> 6;
            Bs[kl][nl] = Bw[(size_t)(k0 + kl) * EDIM + bn + nl];
        }
        __syncthreads();
#pragma unroll
        for (int kk = 0; kk < 16; ++kk) {
            float4 av = *(const float4*)&As[kk][ty * 4];
            float4 bv = *(const float4*)&Bs[kk][tx * 4];
            float a[4] = {av.x, av.y, av.z, av.w};
            float b[4] = {bv.x, bv.y, bv.z, bv.w};
#pragma unroll
            for (int i = 0; i < 4; ++i)
#pragma unroll
                for (int j = 0; j < 4; ++j)
                    acc[i][j] = fmaf(a[i], b[j], acc[i][j]);
        }
        __syncthreads();
    }
#pragma unroll
    for (int i = 0; i < 4; ++i) {
        int r = bm + ty * 4 + i;
#pragma unroll
        for (int j = 0; j < 4; ++j) {
            int c = bn + tx * 4 + j;
            float v = acc[i][j] + bias[c];
            v = (v > 20.f) ? v : log1pf(__expf(v));
            Ct[((size_t)(r >> 11) * EDIM + c) * LD + (r & (LD - 1))] =
                __float2bfloat16(v);
        }
    }
}

// ---------------- scan7: parallel scan + structured-A fast path --------------
// Per block: one (dir, batch, e) channel; 256 threads x 8-step chunks.
// Affine partials (S,P) in registers; Kogge-Stone affine scan (shfl) +
// 4-entry LDS cross-wave compose. Fast path: if A_n == A_0*(n+1) (true for
// this model's A_log = log(1..N)), dA_n = q^(n+1) with q=exp(A_0*dv):
// 8 exps + 15x8 muls instead of 128 exps. Uniform runtime check; generic
// per-n-exp fallback preserved.
__global__ __launch_bounds__(256)
void scan7_k(bf16* __restrict__ xct2, const bf16* __restrict__ dltt2,
             const float* __restrict__ dblt2,
             const float* __restrict__ alog_f, const float* __restrict__ alog_b,
             const float* __restrict__ dp_f, const float* __restrict__ dp_b)
{
    __shared__ float sA[NST];
    __shared__ float sWp[NST][4];
    __shared__ float sWs[NST][4];
    const int gid = blockIdx.x;                 // 0..4095
    const int dir = gid >> 11;
    const int bb  = (gid >> 10) & 1;
    const int e   = gid & (EDIM - 1);
    const float* A_log = dir ? alog_b : alog_f;
    const float* Dp    = dir ? dp_b   : dp_f;
    bf16* xct = xct2 + (size_t)dir * ((size_t)MROWS * EDIM);
    const bf16* dltt = dltt2 + (size_t)dir * ((size_t)MROWS * EDIM);
    const float* bt = dblt2 + (size_t)dir * (2 * 64 * LD) + (size_t)bb * 64 * LD;
    const int tid = threadIdx.x;
    const int wave = tid >> 6, lane = tid & 63;
    const size_t baset = ((size_t)bb * EDIM + e) * LD;
    const int l0 = tid * 8;

    if (tid < NST) sA[tid] = -__expf(A_log[e * NST + tid]);

    float xv[8], dv[8], dx[8];
    {
        bf16x8 xr = *(const bf16x8*)(xct + baset + l0);
        bf16x8 dr = *(const bf16x8*)(dltt + baset + l0);
#pragma unroll
        for (int j = 0; j < 8; ++j) { xv[j] = (float)xr[j]; dv[j] = (float)dr[j]; }
    }
#pragma unroll
    for (int j = 0; j < 8; ++j) dx[j] = dv[j] * xv[j];
    __syncthreads();

    // structured-A detection (uniform across grid; ~free)
    bool linA = true;
    {
        float A1 = sA[0];
#pragma unroll
        for (int n = 1; n < NST; ++n)
            linA = linA && (fabsf(sA[n] - A1 * (float)(n + 1))
                            <= 1e-4f * (float)(n + 1));
    }
    float q[8], dA[8];
    if (linA) {
        float A1 = sA[0];
#pragma unroll
        for (int l = 0; l < 8; ++l) { q[l] = __expf(A1 * dv[l]); dA[l] = q[l]; }
    }

    float y[8] = {};
    for (int n = 0; n < NST; ++n) {
        const float An = sA[n];
        const float* Bp = bt + (size_t)(DTR + n) * LD + l0;
        const float* Cp = bt + (size_t)(DTR + NST + n) * LD + l0;
        float4 b0 = *(const float4*)Bp, b1 = *(const float4*)(Bp + 4);
        float4 c0 = *(const float4*)Cp, c1 = *(const float4*)(Cp + 4);
        float Br[8] = {b0.x,b0.y,b0.z,b0.w, b1.x,b1.y,b1.z,b1.w};
        float Cr[8] = {c0.x,c0.y,c0.z,c0.w, c1.x,c1.y,c1.z,c1.w};

        if (!linA) {
#pragma unroll
            for (int l = 0; l < 8; ++l) dA[l] = __expf(dv[l] * An);
        }

        // single walk: local state S (h_init=0) and cumprod P, in registers
        float S[8], P[8];
        float h = 0.f, pr = 1.f;
#pragma unroll
        for (int l = 0; l < 8; ++l) {
            float a = dA[l];
            pr *= a;
            h = fmaf(a, h, dx[l] * Br[l]);
            P[l] = pr; S[l] = h;
        }

        // Kogge-Stone inclusive affine scan across the 64 chunks of this wave
        float p = pr, s = h;
#pragma unroll
        for (int d = 1; d < 64; d <<= 1) {
            float pp = __shfl_up(p, d, 64);
            float sp = __shfl_up(s, d, 64);
            if (lane >= d) { s = fmaf(sp, p, s); p *= pp; }
        }
        // wave totals -> LDS, compose across waves (ascending order)
        if (lane == 63) { sWp[n][wave] = p; sWs[n][wave] = s; }
        __syncthreads();
        float Hoff = 0.f;
#pragma unroll
        for (int w = 0; w < 3; ++w)
            if (w < wave) Hoff = fmaf(sWp[n][w], Hoff, sWs[n][w]);
        // exclusive prefix for this chunk
        float pprev = __shfl_up(p, 1, 64);
        float sprev = __shfl_up(s, 1, 64);
        float H = (lane == 0) ? Hoff : fmaf(pprev, Hoff, sprev);

#pragma unroll
        for (int l = 0; l < 8; ++l)
            y[l] = fmaf(Cr[l], fmaf(P[l], H, S[l]), y[l]);

        if (linA) {
#pragma unroll
            for (int l = 0; l < 8; ++l) dA[l] *= q[l];
        }
    }

    const float Dv = Dp[e];
    bf16x8 o;
#pragma unroll
    for (int l = 0; l < 8; ++l) o[l] = (__bf16)fmaf(xv[l], Dv, y[l]);
    *(bf16x8*)(xct + baset + l0) = o;
}

// ---------------- layernorm (bf16 in-place), dir0 rows only ------------------
__global__ __launch_bounds__(256)
void ln_k(bf16* __restrict__ m, const float* __restrict__ gg,
          const float* __restrict__ bb)
{
    int row = (blockIdx.x * 256 + threadIdx.x) >> 6;
    int lane = threadIdx.x & 63;
    bf16* r = m + (size_t)row * DMODEL;
    float v[8], s = 0.f, s2 = 0.f;
#pragma unroll
    for (int i = 0; i < 8; ++i) {
        v[i] = __bfloat162float(r[lane + 64 * i]);
        s += v[i]; s2 = fmaf(v[i], v[i], s2);
    }
#pragma unroll
    for (int off = 32; off >= 1; off >>= 1) {
        s  += __shfl_xor(s, off, 64);
        s2 += __shfl_xor(s2, off, 64);
    }
    float mu = s * (1.f / DMODEL);
    float var = s2 * (1.f / DMODEL) - mu * mu;
    float inv = rsqrtf(var + 1e-5f);
#pragma unroll
    for (int i = 0; i < 8; ++i)
        r[lane + 64 * i] = __float2bfloat16(
            (v[i] - mu) * inv * gg[lane + 64 * i] + bb[lane + 64 * i]);
}

__global__ void sentinel_k(float* __restrict__ o)
{
    int i = blockIdx.x * 256 + threadIdx.x;
    o[i] = 100.0f;
}

extern "C" void kernel_launch(void* const* d_in, const int* in_sizes, int n_in,
                              void* d_out, int out_size, void* d_ws, size_t ws_size,
                              hipStream_t stream)
{
    const float* x    = (const float*)d_in[0];
    const float* n1g  = (const float*)d_in[19];
    const float* n1b  = (const float*)d_in[20];
    const float* fw1  = (const float*)d_in[23];
    const float* fb1  = (const float*)d_in[24];
    const float* fw2  = (const float*)d_in[25];
    const float* fb2  = (const float*)d_in[26];
    float* out = (float*)d_out;

    const size_t MiB = 1024 * 1024;
    const size_t SZ_DM = (size_t)MROWS * DMODEL;
    if (ws_size < 46 * MiB) {
        sentinel_k<<<dim3(SZ_DM / 256), dim3(256), 0, stream>>>(out);
        return;
    }

    // ---- 46 MiB layout ----
    char* base = (char*)d_ws;
    bf16* fw1T  = (bf16*)base;                 // [1024][512]        1 MiB
    bf16* fw2T  = (bf16*)(base + 1 * MiB);     // [512][1024]        1 MiB
    bf16* outwT = (bf16*)(base + 2 * MiB);     // [2][512][1024]     2 MiB
    bf16* inwT  = (bf16*)(base + 4 * MiB);     // [2][2048][512]     4 MiB
    bf16* xbf   = (bf16*)(base + 8 * MiB);     // [4096][512]        4 MiB (live thru zgate)
    char* RA    = base + 12 * MiB;             // 16 MiB: xs2 -> dltt2 -> yrow2 -> ffh2
    bf16* xs2   = (bf16*)RA;                   // [2][4096][1024]
    bf16* dltt2 = (bf16*)RA;
    bf16* yrow2 = (bf16*)RA;
    bf16* ffh2  = (bf16*)RA;
    char* RB    = base + 28 * MiB;             // 16 MiB: xct2 -> mbf2(8)
    bf16* xct2  = (bf16*)RB;                   // [2][2][1024][2048]
    bf16* mbf2  = (bf16*)RB;                   // [2][4096][512]
    float* dblt2 = (float*)(base + 44 * MiB);  // [2][2][64][2048]   2 MiB

    const float* inw_f  = (const float*)d_in[1];
    const float* cw_f   = (const float*)d_in[2];
    const float* cb_f   = (const float*)d_in[3];
    const float* xp_f   = (const float*)d_in[4];
    const float* dtw_f  = (const float*)d_in[5];
    const float* dtb_f  = (const float*)d_in[6];
    const float* alog_f = (const float*)d_in[7];
    const float* dp_f   = (const float*)d_in[8];
    const float* outw_f = (const float*)d_in[9];
    const float* inw_b  = (const float*)d_in[10];
    const float* cw_b   = (const float*)d_in[11];
    const float* cb_b   = (const float*)d_in[12];
    const float* xp_b   = (const float*)d_in[13];
    const float* dtw_b  = (const float*)d_in[14];
    const float* dtb_b  = (const float*)d_in[15];
    const float* alog_b = (const float*)d_in[16];
    const float* dp_b   = (const float*)d_in[17];
    const float* outw_b = (const float*)d_in[18];

    dim3 blk(256);
    const size_t U = (size_t)MROWS * EDIM;   // 4,194,304 elems

    // 1. prep: all transposes + xconv
    prep_k<<<dim3(6144), blk, 0, stream>>>(x, xbf, inw_f, inw_b, inwT,
                                           outw_f, outw_b, outwT,
                                           fw1, fw1T, fw2, fw2T);
    // 2. G1: xs2[dir] = x(flip d1) @ in_w[:, :1024]   M=4096 N=1024 K=512
    bgemm3_k<128, 0, true, false><<<dim3(8, 32, 2), blk, 0, stream>>>(
        xbf, 0, DMODEL, inwT, (size_t)2048 * 512, DMODEL, nullptr,
        xs2, U, EDIM, nullptr, 0, nullptr, DMODEL);
    // 3. conv + silu + transpose
    conv2_k<<<dim3(16, 64, 2), blk, 0, stream>>>(xs2, cw_f, cb_f, cw_b, cb_b, xct2);
    // 4. G2
    g2_k<<<dim3(256, 2), blk, 0, stream>>>(xct2, xp_f, xp_b, dblt2);
    // 5. G3 (writes dltt2 over dead xs2)
    g3_k<<<dim3(16, 64, 2), blk, 0, stream>>>(dblt2, dtw_f, dtb_f, dtw_b, dtb_b, dltt2);
    // 6. scan (in-place over xct2)
    scan7_k<<<dim3(4096), blk, 0, stream>>>(xct2, dltt2, dblt2,
                                            alog_f, alog_b, dp_f, dp_b);
    // 7. zgate: yrow2 = silu(x @ inw_z) * y  (writes over dead dltt2)
    zgate_k<<<dim3(8, 64, 2), blk, 0, stream>>>(xbf, inwT, xct2, yrow2);
    // 8. G4: mbf2[dir] = y @ out_w   M=4096 N=512 K=1024
    bgemm3_k<64, 0, false, false><<<dim3(8, 32, 2), blk, 0, stream>>>(
        yrow2, U, EDIM, outwT, (size_t)512 * 1024, EDIM, nullptr,
        mbf2, SZ_DM, DMODEL, nullptr, 0, nullptr, EDIM);
    // 9. LN on dir0 half of mbf2 (in place)
    ln_k<<<dim3(MROWS / 4), blk, 0, stream>>>(mbf2, n1g, n1b);
    // 10. G5: ffh2[dir] = relu(m @ fw1 + fb1)   M=4096 N=1024 K=512
    bgemm3_k<128, 2, false, false><<<dim3(8, 32, 2), blk, 0, stream>>>(
        mbf2, SZ_DM, DMODEL, fw1T, 0, DMODEL, fb1,
        ffh2, U, DFF, nullptr, 0, nullptr, DMODEL);
    // 11. G6 fused (concat-K): out = ffh_f@fw2 + ffh_b@fw2 + 2*fb2 + m_f + m_b
    //     M=4096 N=512 K=2048 (B col = k % 1024, A half1 at ffh2+U)
    bgemm3_k<64, 5, false, true><<<dim3(8, 32, 1), blk, 0, stream>>>(
        ffh2, U, DFF, fw2T, 0, DFF, fb2,
        nullptr, 0, DMODEL, mbf2, SZ_DM, out, 2 * DFF);
}

// Round 3
// 423.411 us; speedup vs baseline: 1.0294x; 1.0294x over previous
//
#include <hip/hip_runtime.h>
#include <hip/hip_bf16.h>
#include <math.h>

// BiMambaEncoderLayer: B=2, L=2048, D_MODEL=512, ED=1024, N=16, DCONV=4,
// DT_RANK=32, D_FF=1024. f32 in/out.
// Round-18:
//  (a) REVERT scan7 -> scan6 (structured-A path regressed 64->74.6us:
//      loop-carried dA chain + in-loop branches killed exp pipelining).
//  (b) conv2_k: vectorize global I/O (bf16x8 loads/stores, was scalar 2B);
//      LDS re-layouted to [67][65]/[64][65] for conflict-free wide access.
//  (c) g2_k: widen A staging to 8B/lane (bf16x4, 128 lanes).
//  bgemm3 (glds16) + fused G6 kept from round-17 (measured neutral vs
//  bgemm2, one fewer dispatch). 11 dispatches, 46 MiB workspace.

#define BD 2
#define LD 2048
#define DMODEL 512
#define EDIM 1024
#define NST 16
#define DTR 32
#define DFF 1024
#define MROWS (BD*LD)   // 4096

typedef __hip_bfloat16 bf16;
typedef __bf16 bf16x8 __attribute__((ext_vector_type(8)));
typedef __bf16 bf16x4 __attribute__((ext_vector_type(4)));
typedef float  f32x4  __attribute__((ext_vector_type(4)));

__device__ __forceinline__ float sig_(float x) { return 1.f / (1.f + __expf(-x)); }

// async 16B global->LDS (wave-uniform LDS base, per-lane global addr)
__device__ __forceinline__ void glds16(const void* g, void* l)
{
    __builtin_amdgcn_global_load_lds(
        (const __attribute__((address_space(1))) void*)g,
        (__attribute__((address_space(3))) void*)l, 16, 0, 0);
}

// ---------------- prep: all weight transposes + x->bf16, one dispatch --------
__global__ __launch_bounds__(256)
void prep_k(const float* __restrict__ x, bf16* __restrict__ xbf,
            const float* __restrict__ inw_f, const float* __restrict__ inw_b,
            bf16* __restrict__ inwT,
            const float* __restrict__ outw_f, const float* __restrict__ outw_b,
            bf16* __restrict__ outwT,
            const float* __restrict__ fw1, bf16* __restrict__ fw1T,
            const float* __restrict__ fw2, bf16* __restrict__ fw2T)
{
    const int bid = blockIdx.x, tid = threadIdx.x;
    if (bid < 2048) {
        size_t i = (size_t)bid * 1024 + tid * 4;
        float4 v = *(const float4*)(x + i);
        bf16* o = xbf + i;
        o[0] = __float2bfloat16(v.x); o[1] = __float2bfloat16(v.y);
        o[2] = __float2bfloat16(v.z); o[3] = __float2bfloat16(v.w);
        return;
    }
    const float* W; bf16* WT; int R, C, cx, ry;
    if (bid < 4096) {
        int d = (bid - 2048) >> 10, t = (bid - 2048) & 1023;
        W = d ? inw_b : inw_f; WT = inwT + (size_t)d * 2048 * 512;
        R = 512; C = 2048; cx = t & 63; ry = t >> 6;
    } else if (bid < 5120) {
        int d = (bid - 4096) >> 9, t = (bid - 4096) & 511;
        W = d ? outw_b : outw_f; WT = outwT + (size_t)d * 512 * 1024;
        R = 1024; C = 512; cx = t & 15; ry = t >> 4;
    } else if (bid < 5632) {
        int t = bid - 5120; W = fw1; WT = fw1T; R = 512; C = 1024;
        cx = t & 31; ry = t >> 5;
    } else {
        int t = bid - 5632; W = fw2; WT = fw2T; R = 1024; C = 512;
        cx = t & 15; ry = t >> 4;
    }
    __shared__ float tt[32][33];
    const int c0 = cx * 32, r0 = ry * 32;
    const int col = tid & 31, rr = tid >> 5;
#pragma unroll
    for (int p = 0; p < 4; ++p)
        tt[p * 8 + rr][col] = W[(size_t)(r0 + p * 8 + rr) * C + c0 + col];
    __syncthreads();
#pragma unroll
    for (int p = 0; p < 4; ++p)
        WT[(size_t)(c0 + p * 8 + rr) * R + r0 + col] =
            __float2bfloat16(tt[col][p * 8 + rr]);
}

// ---------------- bgemm3: 128xBN MFMA GEMM with global_load_lds --------------
// A[M][lda] bf16 (per-dir Astr; FLIPD1 row-flips dir1; CATK: A half0 at A,
// half1 at A+Astr, K=2*KH, B col = k % KH). BT[N][ldb] bf16 (per-dir Bstr).
// MODE: 0 plain bf16 out; 2 relu+bias bf16; 5 f32 out = v + 2*bias + mp[idx]
// + mp[mpStr+idx] (the fused G6).
template<int BN, int MODE, bool FLIPD1, bool CATK>
__global__ __launch_bounds__(256)
void bgemm3_k(const bf16* __restrict__ A, size_t Astr, int lda,
              const bf16* __restrict__ BT, size_t Bstr, int ldb,
              const float* __restrict__ bias,
              bf16* __restrict__ Cb, size_t Cstr, int ldc,
              const bf16* __restrict__ mp, size_t mpStr,
              float* __restrict__ outp, int K)
{
    constexpr int BM = 128;
    constexpr int FRm = 4, FRn = BN / 32;
    constexpr int KH = DFF;   // concat-K half length (1024)
    __shared__ __align__(16) bf16 As[BM][32];
    __shared__ __align__(16) bf16 Bs[BN][32];
    const int tid = threadIdx.x;
    const int dir = blockIdx.z;
    const bool flip = FLIPD1 && (dir == 1);
    const bf16* Ad = A + (CATK ? (size_t)0 : (size_t)dir * Astr);
    const bf16* Bd = BT + (size_t)dir * Bstr;
    const int bm = blockIdx.y * BM, bn = blockIdx.x * BN;
    const int wave = tid >> 6, lane = tid & 63;
    const int wm = (wave >> 1) * 64, wn = (wave & 1) * (BN / 2);
    const int lm = lane & 15, lq = lane >> 4;
    const int lrow = lane >> 2, lcol = (lane & 3) * 8;
    f32x4 acc[FRm][FRn] = {};

    for (int k0 = 0; k0 < K; k0 += 32) {
        const bf16* Ab = Ad;
        int ka = k0;
        if (CATK && k0 >= KH) { Ab = A + Astr; ka = k0 - KH; }
        const int kb = CATK ? (k0 & (KH - 1)) : k0;
        // stage A tile (128x32 bf16 = 8KB): 2 chunks x 4 waves x 1KB
#pragma unroll
        for (int c = 0; c < 2; ++c) {
            int row = c * 64 + wave * 16 + lrow;
            int gm = bm + row;
            if (flip) gm = (gm & ~(LD - 1)) + (LD - 1 - (gm & (LD - 1)));
            glds16(Ab + (size_t)gm * lda + ka + lcol,
                   &As[c * 64 + wave * 16][0]);
        }
        // stage B tile (BNx32 bf16): BN/64 chunks x 4 waves x 1KB
#pragma unroll
        for (int c = 0; c < BN / 64; ++c) {
            int row = c * 64 + wave * 16 + lrow;
            glds16(Bd + (size_t)(bn + row) * ldb + kb + lcol,
                   &Bs[c * 64 + wave * 16][0]);
        }
        __syncthreads();   // drains vmcnt -> staging complete

        bf16x8 af[FRm], bfr[FRn];
#pragma unroll
        for (int i = 0; i < FRm; ++i)
            af[i] = *(const bf16x8*)&As[wm + 16 * i + lm][lq * 8];
#pragma unroll
        for (int j = 0; j < FRn; ++j)
            bfr[j] = *(const bf16x8*)&Bs[wn + 16 * j + lm][lq * 8];
#pragma unroll
        for (int i = 0; i < FRm; ++i)
#pragma unroll
            for (int j = 0; j < FRn; ++j)
                acc[i][j] = __builtin_amdgcn_mfma_f32_16x16x32_bf16(
                    af[i], bfr[j], acc[i][j], 0, 0, 0);
        __syncthreads();
    }

    bf16* Cd = (MODE == 5) ? nullptr : Cb + (size_t)dir * Cstr;
#pragma unroll
    for (int i = 0; i < FRm; ++i) {
#pragma unroll
        for (int j = 0; j < FRn; ++j) {
            int col = bn + wn + 16 * j + lm;
            float bv = (MODE == 2) ? bias[col]
                     : (MODE == 5) ? 2.f * bias[col] : 0.f;
#pragma unroll
            for (int r = 0; r < 4; ++r) {
                int row = bm + wm + 16 * i + lq * 4 + r;
                float v = acc[i][j][r] + bv;
                size_t idx = (size_t)row * ldc + col;
                if (MODE == 0)      Cd[idx] = __float2bfloat16(v);
                else if (MODE == 2) Cd[idx] = __float2bfloat16(fmaxf(v, 0.f));
                else {
                    float m2 = __bfloat162float(mp[idx])
                             + __bfloat162float(mp[mpStr + idx]);
                    outp[idx] = v + m2;
                }
            }
        }
    }
}

// ---------------- zgate: yrow = silu(x(flip?) @ inw_z) * y2t^T ---------------
__global__ __launch_bounds__(256)
void zgate_k(const bf16* __restrict__ xbf, const bf16* __restrict__ inwT,
             const bf16* __restrict__ y2t_all, bf16* __restrict__ yrow_all)
{
    __shared__ __align__(16) bf16 As[64][40];
    __shared__ __align__(16) bf16 Bs[128][40];
    __shared__ __bf16 sy[64][130];
    const int tid = threadIdx.x;
    const int dir = blockIdx.z;
    const bf16* Bd = inwT + (size_t)dir * (2048 * 512) + (size_t)1024 * 512;
    const bf16* y2t = y2t_all + (size_t)dir * ((size_t)MROWS * EDIM);
    bf16* yrow = yrow_all + (size_t)dir * ((size_t)MROWS * EDIM);
    const int bm = blockIdx.y * 64, bn = blockIdx.x * 128;
    const int wave = tid >> 6, lane = tid & 63;
    const int wm = (wave >> 1) * 32, wn = (wave & 1) * 64;
    const int lm = lane & 15, lq = lane >> 4;
    f32x4 acc[2][4] = {};

    for (int k0 = 0; k0 < 512; k0 += 32) {
        {
            int row = tid >> 2, col = (tid & 3) * 8;
            int gm = bm + row;
            if (dir == 1) gm = (gm & ~(LD - 1)) + (LD - 1 - (gm & (LD - 1)));
            *(bf16x8*)&As[row][col] =
                *(const bf16x8*)(xbf + (size_t)gm * 512 + k0 + col);
        }
#pragma unroll
        for (int p = 0; p < 2; ++p) {
            int row = p * 64 + (tid >> 2), col = (tid & 3) * 8;
            *(bf16x8*)&Bs[row][col] =
                *(const bf16x8*)(Bd + (size_t)(bn + row) * 512 + k0 + col);
        }
        __syncthreads();
        bf16x8 af[2], bfr[4];
#pragma unroll
        for (int i = 0; i < 2; ++i)
            af[i] = *(const bf16x8*)&As[wm + 16 * i + lm][lq * 8];
#pragma unroll
        for (int j = 0; j < 4; ++j)
            bfr[j] = *(const bf16x8*)&Bs[wn + 16 * j + lm][lq * 8];
#pragma unroll
        for (int i = 0; i < 2; ++i)
#pragma unroll
            for (int j = 0; j < 4; ++j)
                acc[i][j] = __builtin_amdgcn_mfma_f32_16x16x32_bf16(
                    af[i], bfr[j], acc[i][j], 0, 0, 0);
        __syncthreads();
    }

    {
        const int b = bm >> 11, l0 = bm & (LD - 1);
        int e = tid >> 1, lh = (tid & 1) * 32;
        const bf16* yp = y2t + ((size_t)b * EDIM + bn + e) * LD + l0 + lh;
#pragma unroll
        for (int i = 0; i < 4; ++i) {
            bf16x8 v = *(const bf16x8*)(yp + i * 8);
#pragma unroll
            for (int j = 0; j < 8; ++j) sy[lh + i * 8 + j][e] = v[j];
        }
    }
    __syncthreads();
#pragma unroll
    for (int i = 0; i < 2; ++i) {
#pragma unroll
        for (int j = 0; j < 4; ++j) {
            int col = bn + wn + 16 * j + lm;
#pragma unroll
            for (int r = 0; r < 4; ++r) {
                int row = bm + wm + 16 * i + lq * 4 + r;
                float z = acc[i][j][r];
                float g = z * sig_(z);
                float y = (float)sy[(row - bm)][col - bn];
                yrow[(size_t)row * EDIM + col] = __float2bfloat16(g * y);
            }
        }
    }
}

// ---------------- conv(4)+bias+silu+transpose, dir-merged, vectorized --------
__global__ __launch_bounds__(256)
void conv2_k(const bf16* __restrict__ xs2,
             const float* __restrict__ cw_f, const float* __restrict__ cb_f,
             const float* __restrict__ cw_b, const float* __restrict__ cb_b,
             bf16* __restrict__ xct2)
{
    __shared__ float sxs[67][65];
    __shared__ float sout[64][65];
    const int tid = threadIdx.x;
    const int dir = blockIdx.z;
    const bf16* xs = xs2 + (size_t)dir * ((size_t)MROWS * EDIM);
    const float* w  = dir ? cw_b : cw_f;
    const float* cb = dir ? cb_b : cb_f;
    bf16* xct = xct2 + (size_t)dir * ((size_t)MROWS * EDIM);
    const int e0 = blockIdx.x * 64;
    const int bl0 = blockIdx.y * 64;
    const int lloc0 = bl0 & (LD - 1);
    const int b = bl0 >> 11;
    // load 67 rows x 64 e, bf16x8 per thread (bank-clean: stride 65)
    {
        int c8 = (tid & 7) * 8;
#pragma unroll
        for (int i = 0; i < 3; ++i) {
            int hr = i * 32 + (tid >> 3);
            if (hr < 67) {
                int lr = lloc0 + hr - 3;
                if (lr >= 0) {
                    bf16x8 v = *(const bf16x8*)(xs +
                        (size_t)(bl0 + hr - 3) * EDIM + e0 + c8);
#pragma unroll
                    for (int j = 0; j < 8; ++j) sxs[hr][c8 + j] = (float)v[j];
                } else {
#pragma unroll
                    for (int j = 0; j < 8; ++j) sxs[hr][c8 + j] = 0.f;
                }
            }
        }
    }
    __syncthreads();
    {
        int lr4 = tid >> 6, e = tid & 63;
        float w0 = w[(e0 + e) * 4 + 0], w1 = w[(e0 + e) * 4 + 1];
        float w2 = w[(e0 + e) * 4 + 2], w3 = w[(e0 + e) * 4 + 3];
        float cbv = cb[e0 + e];
#pragma unroll
        for (int i = 0; i < 16; ++i) {
            int lr = i * 4 + lr4;
            float acc = cbv;
            acc = fmaf(sxs[lr + 0][e], w0, acc);
            acc = fmaf(sxs[lr + 1][e], w1, acc);
            acc = fmaf(sxs[lr + 2][e], w2, acc);
            acc = fmaf(sxs[lr + 3][e], w3, acc);
            sout[e][lr] = acc * sig_(acc);
        }
    }
    __syncthreads();
    // store 64 e-rows x 64 l, bf16x8 per thread
    {
        int l8 = (tid & 7) * 8;
#pragma unroll
        for (int i = 0; i < 2; ++i) {
            int er = i * 32 + (tid >> 3);
            bf16x8 o;
#pragma unroll
            for (int j = 0; j < 8; ++j) o[j] = (__bf16)sout[er][l8 + j];
            *(bf16x8*)(xct + ((size_t)b * EDIM + e0 + er) * LD + lloc0 + l8) = o;
        }
    }
}

// ---------------- G2 dir-merged: dbl_t = (xc^T @ xproj)^T --------------------
__global__ __launch_bounds__(256)
void g2_k(const bf16* __restrict__ xct2, const float* __restrict__ xp_f,
          const float* __restrict__ xp_b, float* __restrict__ dblt2)
{
    __shared__ __align__(16) float As[32][18];
    __shared__ __align__(16) float Bs[32][66];
    const int tid = threadIdx.x;
    const int dir = blockIdx.y;
    const bf16* xct = xct2 + (size_t)dir * ((size_t)MROWS * EDIM);
    const float* xproj = dir ? xp_b : xp_f;
    float* dblt = dblt2 + (size_t)dir * (2 * 64 * LD);
    const int r0 = blockIdx.x * 16;
    const int bB = r0 >> 11, l0 = r0 & (LD - 1);
    const int row = tid >> 4, col4 = (tid & 15) * 4;
    float acc[4] = {};

    for (int k0 = 0; k0 < EDIM; k0 += 32) {
        if (tid < 128) {
            int k = tid & 31, ls = (tid >> 5) * 4;
            const bf16* p = xct + ((size_t)bB * EDIM + k0 + k) * LD + l0 + ls;
            bf16x4 v = *(const bf16x4*)p;
            As[k][ls]     = (float)v[0];
            As[k][ls + 1] = (float)v[1];
            As[k][ls + 2] = (float)v[2];
            As[k][ls + 3] = (float)v[3];
        }
        {
            int k = tid >> 3, ns = (tid & 7) * 8;
            const float* p = xproj + (size_t)(k0 + k) * 64 + ns;
            float4 v0 = *(const float4*)p, v1 = *(const float4*)(p + 4);
            float* d = &Bs[k][ns];
            d[0]=v0.x; d[1]=v0.y; d[2]=v0.z; d[3]=v0.w;
            d[4]=v1.x; d[5]=v1.y; d[6]=v1.z; d[7]=v1.w;
        }
        __syncthreads();
#pragma unroll
        for (int kk = 0; kk < 32; ++kk) {
            float a = As[kk][row];
            float4 b4 = *(const float4*)&Bs[kk][col4];
            acc[0] = fmaf(a, b4.x, acc[0]);
            acc[1] = fmaf(a, b4.y, acc[1]);
            acc[2] = fmaf(a, b4.z, acc[2]);
            acc[3] = fmaf(a, b4.w, acc[3]);
        }
        __syncthreads();
    }
#pragma unroll
    for (int j = 0; j < 4; ++j)
        dblt[((size_t)bB * 64 + col4 + j) * LD + l0 + row] = acc[j];
}

// ---------------- G3 dir-merged: dlt_t(bf16) = softplus(...)^T ---------------
__global__ __launch_bounds__(256)
void g3_k(const float* __restrict__ dblt2,
          const float* __restrict__ dtw_f, const float* __restrict__ dtb_f,
          const float* __restrict__ dtw_b, const float* __restrict__ dtb_b,
          bf16* __restrict__ dltt2)
{
    __shared__ __align__(16) float As[16][68];
    __shared__ __align__(16) float Bs[16][68];
    const int tid = threadIdx.x;
    const int dir = blockIdx.z;
    const float* Ap = dblt2 + (size_t)dir * (2 * 64 * LD);
    const float* Bw = dir ? dtw_b : dtw_f;
    const float* bias = dir ? dtb_b : dtb_f;
    bf16* Ct = dltt2 + (size_t)dir * ((size_t)MROWS * EDIM);
    const int bm = blockIdx.y * 64;
    const int bn = blockIdx.x * 64;
    const int bB = bm >> 11, l0 = bm & (LD - 1);
    const int tx = tid & 15, ty = tid >> 4;
    float acc[4][4] = {};

    for (int k0 = 0; k0 < DTR; k0 += 16) {
#pragma unroll
        for (int i = 0; i < 4; ++i) {
            int k = i * 4 + (tid >> 6), ll = tid & 63;
            As[k][ll] = Ap[((size_t)bB * 64 + k0 + k) * LD + l0 + ll];
        }
#pragma unroll
        for (int i = 0; i < 4; ++i) {
            int idx = tid + 256 * i;
            int nl = idx & 63, kl = idx >> 6;
            Bs[kl][nl] = Bw[(size_t)(k0 + kl) * EDIM + bn + nl];
        }
        __syncthreads();
#pragma unroll
        for (int kk = 0; kk < 16; ++kk) {
            float4 av = *(const float4*)&As[kk][ty * 4];
            float4 bv = *(const float4*)&Bs[kk][tx * 4];
            float a[4] = {av.x, av.y, av.z, av.w};
            float b[4] = {bv.x, bv.y, bv.z, bv.w};
#pragma unroll
            for (int i = 0; i < 4; ++i)
#pragma unroll
                for (int j = 0; j < 4; ++j)
                    acc[i][j] = fmaf(a[i], b[j], acc[i][j]);
        }
        __syncthreads();
    }
#pragma unroll
    for (int i = 0; i < 4; ++i) {
        int r = bm + ty * 4 + i;
#pragma unroll
        for (int j = 0; j < 4; ++j) {
            int c = bn + tx * 4 + j;
            float v = acc[i][j] + bias[c];
            v = (v > 20.f) ? v : log1pf(__expf(v));
            Ct[((size_t)(r >> 11) * EDIM + c) * LD + (r & (LD - 1))] =
                __float2bfloat16(v);
        }
    }
}

// ---------------- scan6 dir-merged: 256 chunks x 8 steps, parallel scan ------
// (round-16 version, verbatim — measured 64us / VALUBusy 75%)
__global__ __launch_bounds__(256)
void scan6_k(bf16* __restrict__ xct2, const bf16* __restrict__ dltt2,
             const float* __restrict__ dblt2,
             const float* __restrict__ alog_f, const float* __restrict__ alog_b,
             const float* __restrict__ dp_f, const float* __restrict__ dp_b)
{
    __shared__ float sA[NST];
    __shared__ float sWp[NST][4];
    __shared__ float sWs[NST][4];
    const int gid = blockIdx.x;                 // 0..4095
    const int dir = gid >> 11;
    const int bb  = (gid >> 10) & 1;
    const int e   = gid & (EDIM - 1);
    const float* A_log = dir ? alog_b : alog_f;
    const float* Dp    = dir ? dp_b   : dp_f;
    bf16* xct = xct2 + (size_t)dir * ((size_t)MROWS * EDIM);
    const bf16* dltt = dltt2 + (size_t)dir * ((size_t)MROWS * EDIM);
    const float* bt = dblt2 + (size_t)dir * (2 * 64 * LD) + (size_t)bb * 64 * LD;
    const int tid = threadIdx.x;
    const int wave = tid >> 6, lane = tid & 63;
    const size_t baset = ((size_t)bb * EDIM + e) * LD;
    const int l0 = tid * 8;

    if (tid < NST) sA[tid] = -__expf(A_log[e * NST + tid]);

    float xv[8], dv[8], dx[8];
    {
        bf16x8 xr = *(const bf16x8*)(xct + baset + l0);
        bf16x8 dr = *(const bf16x8*)(dltt + baset + l0);
#pragma unroll
        for (int j = 0; j < 8; ++j) { xv[j] = (float)xr[j]; dv[j] = (float)dr[j]; }
    }
#pragma unroll
    for (int j = 0; j < 8; ++j) dx[j] = dv[j] * xv[j];
    __syncthreads();

    float y[8] = {};
    for (int n = 0; n < NST; ++n) {
        const float An = sA[n];
        const float* Bp = bt + (size_t)(DTR + n) * LD + l0;
        const float* Cp = bt + (size_t)(DTR + NST + n) * LD + l0;
        float4 b0 = *(const float4*)Bp, b1 = *(const float4*)(Bp + 4);
        float4 c0 = *(const float4*)Cp, c1 = *(const float4*)(Cp + 4);
        float Br[8] = {b0.x,b0.y,b0.z,b0.w, b1.x,b1.y,b1.z,b1.w};
        float Cr[8] = {c0.x,c0.y,c0.z,c0.w, c1.x,c1.y,c1.z,c1.w};

        // single walk: local state S (h_init=0) and cumprod P, in registers
        float S[8], P[8];
        float h = 0.f, pr = 1.f;
#pragma unroll
        for (int l = 0; l < 8; ++l) {
            float a = __expf(dv[l] * An);
            pr *= a;
            h = fmaf(a, h, dx[l] * Br[l]);
            P[l] = pr; S[l] = h;
        }

        // Kogge-Stone inclusive affine scan across the 64 chunks of this wave
        float p = pr, s = h;
#pragma unroll
        for (int d = 1; d < 64; d <<= 1) {
            float pp = __shfl_up(p, d, 64);
            float sp = __shfl_up(s, d, 64);
            if (lane >= d) { s = fmaf(sp, p, s); p *= pp; }
        }
        // wave totals -> LDS, compose across waves (ascending order)
        if (lane == 63) { sWp[n][wave] = p; sWs[n][wave] = s; }
        __syncthreads();
        float Hoff = 0.f;
#pragma unroll
        for (int w = 0; w < 3; ++w)
            if (w < wave) Hoff = fmaf(sWp[n][w], Hoff, sWs[n][w]);
        // exclusive prefix for this chunk
        float pprev = __shfl_up(p, 1, 64);
        float sprev = __shfl_up(s, 1, 64);
        float H = (lane == 0) ? Hoff : fmaf(pprev, Hoff, sprev);

#pragma unroll
        for (int l = 0; l < 8; ++l)
            y[l] = fmaf(Cr[l], fmaf(P[l], H, S[l]), y[l]);
    }

    const float Dv = Dp[e];
    bf16x8 o;
#pragma unroll
    for (int l = 0; l < 8; ++l) o[l] = (__bf16)fmaf(xv[l], Dv, y[l]);
    *(bf16x8*)(xct + baset + l0) = o;
}

// ---------------- layernorm (bf16 in-place), dir0 rows only ------------------
__global__ __launch_bounds__(256)
void ln_k(bf16* __restrict__ m, const float* __restrict__ gg,
          const float* __restrict__ bb)
{
    int row = (blockIdx.x * 256 + threadIdx.x) >> 6;
    int lane = threadIdx.x & 63;
    bf16* r = m + (size_t)row * DMODEL;
    float v[8], s = 0.f, s2 = 0.f;
#pragma unroll
    for (int i = 0; i < 8; ++i) {
        v[i] = __bfloat162float(r[lane + 64 * i]);
        s += v[i]; s2 = fmaf(v[i], v[i], s2);
    }
#pragma unroll
    for (int off = 32; off >= 1; off >>= 1) {
        s  += __shfl_xor(s, off, 64);
        s2 += __shfl_xor(s2, off, 64);
    }
    float mu = s * (1.f / DMODEL);
    float var = s2 * (1.f / DMODEL) - mu * mu;
    float inv = rsqrtf(var + 1e-5f);
#pragma unroll
    for (int i = 0; i < 8; ++i)
        r[lane + 64 * i] = __float2bfloat16(
            (v[i] - mu) * inv * gg[lane + 64 * i] + bb[lane + 64 * i]);
}

__global__ void sentinel_k(float* __restrict__ o)
{
    int i = blockIdx.x * 256 + threadIdx.x;
    o[i] = 100.0f;
}

extern "C" void kernel_launch(void* const* d_in, const int* in_sizes, int n_in,
                              void* d_out, int out_size, void* d_ws, size_t ws_size,
                              hipStream_t stream)
{
    const float* x    = (const float*)d_in[0];
    const float* n1g  = (const float*)d_in[19];
    const float* n1b  = (const float*)d_in[20];
    const float* fw1  = (const float*)d_in[23];
    const float* fb1  = (const float*)d_in[24];
    const float* fw2  = (const float*)d_in[25];
    const float* fb2  = (const float*)d_in[26];
    float* out = (float*)d_out;

    const size_t MiB = 1024 * 1024;
    const size_t SZ_DM = (size_t)MROWS * DMODEL;
    if (ws_size < 46 * MiB) {
        sentinel_k<<<dim3(SZ_DM / 256), dim3(256), 0, stream>>>(out);
        return;
    }

    // ---- 46 MiB layout ----
    char* base = (char*)d_ws;
    bf16* fw1T  = (bf16*)base;                 // [1024][512]        1 MiB
    bf16* fw2T  = (bf16*)(base + 1 * MiB);     // [512][1024]        1 MiB
    bf16* outwT = (bf16*)(base + 2 * MiB);     // [2][512][1024]     2 MiB
    bf16* inwT  = (bf16*)(base + 4 * MiB);     // [2][2048][512]     4 MiB
    bf16* xbf   = (bf16*)(base + 8 * MiB);     // [4096][512]        4 MiB (live thru zgate)
    char* RA    = base + 12 * MiB;             // 16 MiB: xs2 -> dltt2 -> yrow2 -> ffh2
    bf16* xs2   = (bf16*)RA;                   // [2][4096][1024]
    bf16* dltt2 = (bf16*)RA;
    bf16* yrow2 = (bf16*)RA;
    bf16* ffh2  = (bf16*)RA;
    char* RB    = base + 28 * MiB;             // 16 MiB: xct2 -> mbf2(8)
    bf16* xct2  = (bf16*)RB;                   // [2][2][1024][2048]
    bf16* mbf2  = (bf16*)RB;                   // [2][4096][512]
    float* dblt2 = (float*)(base + 44 * MiB);  // [2][2][64][2048]   2 MiB

    const float* inw_f  = (const float*)d_in[1];
    const float* cw_f   = (const float*)d_in[2];
    const float* cb_f   = (const float*)d_in[3];
    const float* xp_f   = (const float*)d_in[4];
    const float* dtw_f  = (const float*)d_in[5];
    const float* dtb_f  = (const float*)d_in[6];
    const float* alog_f = (const float*)d_in[7];
    const float* dp_f   = (const float*)d_in[8];
    const float* outw_f = (const float*)d_in[9];
    const float* inw_b  = (const float*)d_in[10];
    const float* cw_b   = (const float*)d_in[11];
    const float* cb_b   = (const float*)d_in[12];
    const float* xp_b   = (const float*)d_in[13];
    const float* dtw_b  = (const float*)d_in[14];
    const float* dtb_b  = (const float*)d_in[15];
    const float* alog_b = (const float*)d_in[16];
    const float* dp_b   = (const float*)d_in[17];
    const float* outw_b = (const float*)d_in[18];

    dim3 blk(256);
    const size_t U = (size_t)MROWS * EDIM;   // 4,194,304 elems

    // 1. prep: all transposes + xconv
    prep_k<<<dim3(6144), blk, 0, stream>>>(x, xbf, inw_f, inw_b, inwT,
                                           outw_f, outw_b, outwT,
                                           fw1, fw1T, fw2, fw2T);
    // 2. G1: xs2[dir] = x(flip d1) @ in_w[:, :1024]   M=4096 N=1024 K=512
    bgemm3_k<128, 0, true, false><<<dim3(8, 32, 2), blk, 0, stream>>>(
        xbf, 0, DMODEL, inwT, (size_t)2048 * 512, DMODEL, nullptr,
        xs2, U, EDIM, nullptr, 0, nullptr, DMODEL);
    // 3. conv + silu + transpose
    conv2_k<<<dim3(16, 64, 2), blk, 0, stream>>>(xs2, cw_f, cb_f, cw_b, cb_b, xct2);
    // 4. G2
    g2_k<<<dim3(256, 2), blk, 0, stream>>>(xct2, xp_f, xp_b, dblt2);
    // 5. G3 (writes dltt2 over dead xs2)
    g3_k<<<dim3(16, 64, 2), blk, 0, stream>>>(dblt2, dtw_f, dtb_f, dtw_b, dtb_b, dltt2);
    // 6. scan (in-place over xct2)
    scan6_k<<<dim3(4096), blk, 0, stream>>>(xct2, dltt2, dblt2,
                                            alog_f, alog_b, dp_f, dp_b);
    // 7. zgate: yrow2 = silu(x @ inw_z) * y  (writes over dead dltt2)
    zgate_k<<<dim3(8, 64, 2), blk, 0, stream>>>(xbf, inwT, xct2, yrow2);
    // 8. G4: mbf2[dir] = y @ out_w   M=4096 N=512 K=1024
    bgemm3_k<64, 0, false, false><<<dim3(8, 32, 2), blk, 0, stream>>>(
        yrow2, U, EDIM, outwT, (size_t)512 * 1024, EDIM, nullptr,
        mbf2, SZ_DM, DMODEL, nullptr, 0, nullptr, EDIM);
    // 9. LN on dir0 half of mbf2 (in place)
    ln_k<<<dim3(MROWS / 4), blk, 0, stream>>>(mbf2, n1g, n1b);
    // 10. G5: ffh2[dir] = relu(m @ fw1 + fb1)   M=4096 N=1024 K=512
    bgemm3_k<128, 2, false, false><<<dim3(8, 32, 2), blk, 0, stream>>>(
        mbf2, SZ_DM, DMODEL, fw1T, 0, DMODEL, fb1,
        ffh2, U, DFF, nullptr, 0, nullptr, DMODEL);
    // 11. G6 fused (concat-K): out = ffh_f@fw2 + ffh_b@fw2 + 2*fb2 + m_f + m_b
    //     M=4096 N=512 K=2048 (B col = k % 1024, A half1 at ffh2+U)
    bgemm3_k<64, 5, false, true><<<dim3(8, 32, 1), blk, 0, stream>>>(
        ffh2, U, DFF, fw2T, 0, DFF, fb2,
        nullptr, 0, DMODEL, mbf2, SZ_DM, out, 2 * DFF);
}

// Round 4
// 372.190 us; speedup vs baseline: 1.1711x; 1.1376x over previous
//
#include <hip/hip_runtime.h>
#include <hip/hip_bf16.h>
#include <math.h>

// BiMambaEncoderLayer: B=2, L=2048, D_MODEL=512, ED=1024, N=16, DCONV=4,
// DT_RANK=32, D_FF=1024. f32 in/out.
// Round-19: G2/G3 moved to MFMA.
//  - g2_k (67us, VALU 12%, 9.5M bank-conflicts) -> g2m_k: MFMA 64x64xK1024,
//    A transposed in-LDS from xct2 (f32 [64][33], <=2-way banks), B=xpT bf16.
//    Writes only dblt rows 32..63 (scan B/C) + NEW row-major dbldt[l][32] f32
//    (dt rows were only read by g3 -> never materialized transposed).
//  - g3_k (67us, scalar VALU) -> g3m_k: single mfma_16x16x32 K-step,
//    A=dbldt row-major, B=dtwT bf16, softplus epilogue, LDS-transposed
//    coalesced bf16x8 stores to dltt.
//  - prep_k: +xproj^T and +dtw^T transposes (192 extra blocks).
//  scan6 (64us, known-good) / bgemm3 / conv2 / zgate / ln unchanged.
//  11 dispatches, 48.4 MiB workspace (threshold 49; ws proven >=50).

#define BD 2
#define LD 2048
#define DMODEL 512
#define EDIM 1024
#define NST 16
#define DTR 32
#define DFF 1024
#define MROWS (BD*LD)   // 4096

typedef __hip_bfloat16 bf16;
typedef __bf16 bf16x8 __attribute__((ext_vector_type(8)));
typedef __bf16 bf16x4 __attribute__((ext_vector_type(4)));
typedef float  f32x4  __attribute__((ext_vector_type(4)));

__device__ __forceinline__ float sig_(float x) { return 1.f / (1.f + __expf(-x)); }

// async 16B global->LDS (wave-uniform LDS base, per-lane global addr)
__device__ __forceinline__ void glds16(const void* g, void* l)
{
    __builtin_amdgcn_global_load_lds(
        (const __attribute__((address_space(1))) void*)g,
        (__attribute__((address_space(3))) void*)l, 16, 0, 0);
}

// ---------------- prep: all weight transposes + x->bf16, one dispatch --------
// [0,2048) xconv | [2048,4096) inwT | [4096,5120) outwT | [5120,5632) fw1T |
// [5632,6144) fw2T | [6144,6272) xpT | [6272,6336) dtwT
__global__ __launch_bounds__(256)
void prep_k(const float* __restrict__ x, bf16* __restrict__ xbf,
            const float* __restrict__ inw_f, const float* __restrict__ inw_b,
            bf16* __restrict__ inwT,
            const float* __restrict__ outw_f, const float* __restrict__ outw_b,
            bf16* __restrict__ outwT,
            const float* __restrict__ fw1, bf16* __restrict__ fw1T,
            const float* __restrict__ fw2, bf16* __restrict__ fw2T,
            const float* __restrict__ xp_f, const float* __restrict__ xp_b,
            bf16* __restrict__ xpT,
            const float* __restrict__ dtw_f, const float* __restrict__ dtw_b,
            bf16* __restrict__ dtwT)
{
    const int bid = blockIdx.x, tid = threadIdx.x;
    if (bid < 2048) {
        size_t i = (size_t)bid * 1024 + tid * 4;
        float4 v = *(const float4*)(x + i);
        bf16* o = xbf + i;
        o[0] = __float2bfloat16(v.x); o[1] = __float2bfloat16(v.y);
        o[2] = __float2bfloat16(v.z); o[3] = __float2bfloat16(v.w);
        return;
    }
    const float* W; bf16* WT; int R, C, cx, ry;
    if (bid < 4096) {
        int d = (bid - 2048) >> 10, t = (bid - 2048) & 1023;
        W = d ? inw_b : inw_f; WT = inwT + (size_t)d * 2048 * 512;
        R = 512; C = 2048; cx = t & 63; ry = t >> 6;
    } else if (bid < 5120) {
        int d = (bid - 4096) >> 9, t = (bid - 4096) & 511;
        W = d ? outw_b : outw_f; WT = outwT + (size_t)d * 512 * 1024;
        R = 1024; C = 512; cx = t & 15; ry = t >> 4;
    } else if (bid < 5632) {
        int t = bid - 5120; W = fw1; WT = fw1T; R = 512; C = 1024;
        cx = t & 31; ry = t >> 5;
    } else if (bid < 6144) {
        int t = bid - 5632; W = fw2; WT = fw2T; R = 1024; C = 512;
        cx = t & 15; ry = t >> 4;
    } else if (bid < 6272) {
        int d = (bid - 6144) >> 6, t = (bid - 6144) & 63;
        W = d ? xp_b : xp_f; WT = xpT + (size_t)d * 64 * 1024;
        R = 1024; C = 64; cx = t & 1; ry = t >> 1;
    } else {
        int d = (bid - 6272) >> 5, t = (bid - 6272) & 31;
        W = d ? dtw_b : dtw_f; WT = dtwT + (size_t)d * 1024 * DTR;
        R = 32; C = 1024; cx = t; ry = 0;
    }
    __shared__ float tt[32][33];
    const int c0 = cx * 32, r0 = ry * 32;
    const int col = tid & 31, rr = tid >> 5;
#pragma unroll
    for (int p = 0; p < 4; ++p)
        tt[p * 8 + rr][col] = W[(size_t)(r0 + p * 8 + rr) * C + c0 + col];
    __syncthreads();
#pragma unroll
    for (int p = 0; p < 4; ++p)
        WT[(size_t)(c0 + p * 8 + rr) * R + r0 + col] =
            __float2bfloat16(tt[col][p * 8 + rr]);
}

// ---------------- bgemm3: 128xBN MFMA GEMM with global_load_lds --------------
template<int BN, int MODE, bool FLIPD1, bool CATK>
__global__ __launch_bounds__(256)
void bgemm3_k(const bf16* __restrict__ A, size_t Astr, int lda,
              const bf16* __restrict__ BT, size_t Bstr, int ldb,
              const float* __restrict__ bias,
              bf16* __restrict__ Cb, size_t Cstr, int ldc,
              const bf16* __restrict__ mp, size_t mpStr,
              float* __restrict__ outp, int K)
{
    constexpr int BM = 128;
    constexpr int FRm = 4, FRn = BN / 32;
    constexpr int KH = DFF;   // concat-K half length (1024)
    __shared__ __align__(16) bf16 As[BM][32];
    __shared__ __align__(16) bf16 Bs[BN][32];
    const int tid = threadIdx.x;
    const int dir = blockIdx.z;
    const bool flip = FLIPD1 && (dir == 1);
    const bf16* Ad = A + (CATK ? (size_t)0 : (size_t)dir * Astr);
    const bf16* Bd = BT + (size_t)dir * Bstr;
    const int bm = blockIdx.y * BM, bn = blockIdx.x * BN;
    const int wave = tid >> 6, lane = tid & 63;
    const int wm = (wave >> 1) * 64, wn = (wave & 1) * (BN / 2);
    const int lm = lane & 15, lq = lane >> 4;
    const int lrow = lane >> 2, lcol = (lane & 3) * 8;
    f32x4 acc[FRm][FRn] = {};

    for (int k0 = 0; k0 < K; k0 += 32) {
        const bf16* Ab = Ad;
        int ka = k0;
        if (CATK && k0 >= KH) { Ab = A + Astr; ka = k0 - KH; }
        const int kb = CATK ? (k0 & (KH - 1)) : k0;
#pragma unroll
        for (int c = 0; c < 2; ++c) {
            int row = c * 64 + wave * 16 + lrow;
            int gm = bm + row;
            if (flip) gm = (gm & ~(LD - 1)) + (LD - 1 - (gm & (LD - 1)));
            glds16(Ab + (size_t)gm * lda + ka + lcol,
                   &As[c * 64 + wave * 16][0]);
        }
#pragma unroll
        for (int c = 0; c < BN / 64; ++c) {
            int row = c * 64 + wave * 16 + lrow;
            glds16(Bd + (size_t)(bn + row) * ldb + kb + lcol,
                   &Bs[c * 64 + wave * 16][0]);
        }
        __syncthreads();   // drains vmcnt -> staging complete

        bf16x8 af[FRm], bfr[FRn];
#pragma unroll
        for (int i = 0; i < FRm; ++i)
            af[i] = *(const bf16x8*)&As[wm + 16 * i + lm][lq * 8];
#pragma unroll
        for (int j = 0; j < FRn; ++j)
            bfr[j] = *(const bf16x8*)&Bs[wn + 16 * j + lm][lq * 8];
#pragma unroll
        for (int i = 0; i < FRm; ++i)
#pragma unroll
            for (int j = 0; j < FRn; ++j)
                acc[i][j] = __builtin_amdgcn_mfma_f32_16x16x32_bf16(
                    af[i], bfr[j], acc[i][j], 0, 0, 0);
        __syncthreads();
    }

    bf16* Cd = (MODE == 5) ? nullptr : Cb + (size_t)dir * Cstr;
#pragma unroll
    for (int i = 0; i < FRm; ++i) {
#pragma unroll
        for (int j = 0; j < FRn; ++j) {
            int col = bn + wn + 16 * j + lm;
            float bv = (MODE == 2) ? bias[col]
                     : (MODE == 5) ? 2.f * bias[col] : 0.f;
#pragma unroll
            for (int r = 0; r < 4; ++r) {
                int row = bm + wm + 16 * i + lq * 4 + r;
                float v = acc[i][j][r] + bv;
                size_t idx = (size_t)row * ldc + col;
                if (MODE == 0)      Cd[idx] = __float2bfloat16(v);
                else if (MODE == 2) Cd[idx] = __float2bfloat16(fmaxf(v, 0.f));
                else {
                    float m2 = __bfloat162float(mp[idx])
                             + __bfloat162float(mp[mpStr + idx]);
                    outp[idx] = v + m2;
                }
            }
        }
    }
}

// ---------------- zgate: yrow = silu(x(flip?) @ inw_z) * y2t^T ---------------
__global__ __launch_bounds__(256)
void zgate_k(const bf16* __restrict__ xbf, const bf16* __restrict__ inwT,
             const bf16* __restrict__ y2t_all, bf16* __restrict__ yrow_all)
{
    __shared__ __align__(16) bf16 As[64][40];
    __shared__ __align__(16) bf16 Bs[128][40];
    __shared__ __bf16 sy[64][130];
    const int tid = threadIdx.x;
    const int dir = blockIdx.z;
    const bf16* Bd = inwT + (size_t)dir * (2048 * 512) + (size_t)1024 * 512;
    const bf16* y2t = y2t_all + (size_t)dir * ((size_t)MROWS * EDIM);
    bf16* yrow = yrow_all + (size_t)dir * ((size_t)MROWS * EDIM);
    const int bm = blockIdx.y * 64, bn = blockIdx.x * 128;
    const int wave = tid >> 6, lane = tid & 63;
    const int wm = (wave >> 1) * 32, wn = (wave & 1) * 64;
    const int lm = lane & 15, lq = lane >> 4;
    f32x4 acc[2][4] = {};

    for (int k0 = 0; k0 < 512; k0 += 32) {
        {
            int row = tid >> 2, col = (tid & 3) * 8;
            int gm = bm + row;
            if (dir == 1) gm = (gm & ~(LD - 1)) + (LD - 1 - (gm & (LD - 1)));
            *(bf16x8*)&As[row][col] =
                *(const bf16x8*)(xbf + (size_t)gm * 512 + k0 + col);
        }
#pragma unroll
        for (int p = 0; p < 2; ++p) {
            int row = p * 64 + (tid >> 2), col = (tid & 3) * 8;
            *(bf16x8*)&Bs[row][col] =
                *(const bf16x8*)(Bd + (size_t)(bn + row) * 512 + k0 + col);
        }
        __syncthreads();
        bf16x8 af[2], bfr[4];
#pragma unroll
        for (int i = 0; i < 2; ++i)
            af[i] = *(const bf16x8*)&As[wm + 16 * i + lm][lq * 8];
#pragma unroll
        for (int j = 0; j < 4; ++j)
            bfr[j] = *(const bf16x8*)&Bs[wn + 16 * j + lm][lq * 8];
#pragma unroll
        for (int i = 0; i < 2; ++i)
#pragma unroll
            for (int j = 0; j < 4; ++j)
                acc[i][j] = __builtin_amdgcn_mfma_f32_16x16x32_bf16(
                    af[i], bfr[j], acc[i][j], 0, 0, 0);
        __syncthreads();
    }

    {
        const int b = bm >> 11, l0 = bm & (LD - 1);
        int e = tid >> 1, lh = (tid & 1) * 32;
        const bf16* yp = y2t + ((size_t)b * EDIM + bn + e) * LD + l0 + lh;
#pragma unroll
        for (int i = 0; i < 4; ++i) {
            bf16x8 v = *(const bf16x8*)(yp + i * 8);
#pragma unroll
            for (int j = 0; j < 8; ++j) sy[lh + i * 8 + j][e] = v[j];
        }
    }
    __syncthreads();
#pragma unroll
    for (int i = 0; i < 2; ++i) {
#pragma unroll
        for (int j = 0; j < 4; ++j) {
            int col = bn + wn + 16 * j + lm;
#pragma unroll
            for (int r = 0; r < 4; ++r) {
                int row = bm + wm + 16 * i + lq * 4 + r;
                float z = acc[i][j][r];
                float g = z * sig_(z);
                float y = (float)sy[(row - bm)][col - bn];
                yrow[(size_t)row * EDIM + col] = __float2bfloat16(g * y);
            }
        }
    }
}

// ---------------- conv(4)+bias+silu+transpose, dir-merged, vectorized --------
__global__ __launch_bounds__(256)
void conv2_k(const bf16* __restrict__ xs2,
             const float* __restrict__ cw_f, const float* __restrict__ cb_f,
             const float* __restrict__ cw_b, const float* __restrict__ cb_b,
             bf16* __restrict__ xct2)
{
    __shared__ float sxs[67][65];
    __shared__ float sout[64][65];
    const int tid = threadIdx.x;
    const int dir = blockIdx.z;
    const bf16* xs = xs2 + (size_t)dir * ((size_t)MROWS * EDIM);
    const float* w  = dir ? cw_b : cw_f;
    const float* cb = dir ? cb_b : cb_f;
    bf16* xct = xct2 + (size_t)dir * ((size_t)MROWS * EDIM);
    const int e0 = blockIdx.x * 64;
    const int bl0 = blockIdx.y * 64;
    const int lloc0 = bl0 & (LD - 1);
    const int b = bl0 >> 11;
    {
        int c8 = (tid & 7) * 8;
#pragma unroll
        for (int i = 0; i < 3; ++i) {
            int hr = i * 32 + (tid >> 3);
            if (hr < 67) {
                int lr = lloc0 + hr - 3;
                if (lr >= 0) {
                    bf16x8 v = *(const bf16x8*)(xs +
                        (size_t)(bl0 + hr - 3) * EDIM + e0 + c8);
#pragma unroll
                    for (int j = 0; j < 8; ++j) sxs[hr][c8 + j] = (float)v[j];
                } else {
#pragma unroll
                    for (int j = 0; j < 8; ++j) sxs[hr][c8 + j] = 0.f;
                }
            }
        }
    }
    __syncthreads();
    {
        int lr4 = tid >> 6, e = tid & 63;
        float w0 = w[(e0 + e) * 4 + 0], w1 = w[(e0 + e) * 4 + 1];
        float w2 = w[(e0 + e) * 4 + 2], w3 = w[(e0 + e) * 4 + 3];
        float cbv = cb[e0 + e];
#pragma unroll
        for (int i = 0; i < 16; ++i) {
            int lr = i * 4 + lr4;
            float acc = cbv;
            acc = fmaf(sxs[lr + 0][e], w0, acc);
            acc = fmaf(sxs[lr + 1][e], w1, acc);
            acc = fmaf(sxs[lr + 2][e], w2, acc);
            acc = fmaf(sxs[lr + 3][e], w3, acc);
            sout[e][lr] = acc * sig_(acc);
        }
    }
    __syncthreads();
    {
        int l8 = (tid & 7) * 8;
#pragma unroll
        for (int i = 0; i < 2; ++i) {
            int er = i * 32 + (tid >> 3);
            bf16x8 o;
#pragma unroll
            for (int j = 0; j < 8; ++j) o[j] = (__bf16)sout[er][l8 + j];
            *(bf16x8*)(xct + ((size_t)b * EDIM + e0 + er) * LD + lloc0 + l8) = o;
        }
    }
}

// ---------------- g2m: MFMA dbl = xc @ xproj (dt rows row-major) -------------
// M=4096(l), N=64, K=1024(e). A transposed in-LDS from xct2[e][l].
// Outputs: dblt rows 32..63 ([n][l] f32, for scan) + dbldt [l][32] f32 (g3).
__global__ __launch_bounds__(256)
void g2m_k(const bf16* __restrict__ xct2, const bf16* __restrict__ xpT2,
           float* __restrict__ dblt2, float* __restrict__ dbldt2)
{
    __shared__ float As[64][33];            // [l][e] transposed, <=2-way banks
    __shared__ __align__(16) bf16 Bs[64][32];
    __shared__ float sC[32][65];            // n-rows 32..63 staging
    const int tid = threadIdx.x;
    const int dir = blockIdx.z;
    const bf16* xct = xct2 + (size_t)dir * ((size_t)MROWS * EDIM);
    const bf16* xpT = xpT2 + (size_t)dir * (64 * 1024);
    float* dblt = dblt2 + (size_t)dir * (2 * 64 * LD);
    float* dbldt = dbldt2 + (size_t)dir * (2 * 2048 * DTR);
    const int bm = blockIdx.y * 64;
    const int bB = bm >> 11, l0 = bm & (LD - 1);
    const int wave = tid >> 6, lane = tid & 63;
    const int wm = (wave >> 1) * 32, wn = (wave & 1) * 32;
    const int lm = lane & 15, lq = lane >> 4;
    const int er = tid >> 3, l8 = (tid & 7) * 8;   // A-stage coords
    f32x4 acc[2][2] = {};

    for (int k0 = 0; k0 < EDIM; k0 += 32) {
        // B stage (async): wave covers 16 rows x 64B
        glds16(xpT + (size_t)(wave * 16 + (lane >> 2)) * 1024 + k0 + (lane & 3) * 8,
               &Bs[wave * 16][0]);
        // A stage: transpose xct[e][l] -> As[l][e] (f32)
        {
            bf16x8 v = *(const bf16x8*)(xct +
                ((size_t)bB * EDIM + k0 + er) * LD + l0 + l8);
#pragma unroll
            for (int j = 0; j < 8; ++j) As[l8 + j][er] = (float)v[j];
        }
        __syncthreads();
        bf16x8 af[2], bfr[2];
#pragma unroll
        for (int i = 0; i < 2; ++i) {
            int row = wm + 16 * i + lm;
#pragma unroll
            for (int j = 0; j < 8; ++j) af[i][j] = (__bf16)As[row][lq * 8 + j];
        }
#pragma unroll
        for (int j = 0; j < 2; ++j)
            bfr[j] = *(const bf16x8*)&Bs[wn + 16 * j + lm][lq * 8];
#pragma unroll
        for (int i = 0; i < 2; ++i)
#pragma unroll
            for (int j = 0; j < 2; ++j)
                acc[i][j] = __builtin_amdgcn_mfma_f32_16x16x32_bf16(
                    af[i], bfr[j], acc[i][j], 0, 0, 0);
        __syncthreads();
    }
    if (wn == 0) {
        // dt cols 0..31 -> dbldt[l][n] (row-major, 64B-coalesced per lm group)
#pragma unroll
        for (int i = 0; i < 2; ++i)
#pragma unroll
            for (int j = 0; j < 2; ++j) {
                int col = 16 * j + lm;
#pragma unroll
                for (int r = 0; r < 4; ++r) {
                    int row = wm + 16 * i + lq * 4 + r;
                    dbldt[(size_t)(bB * 2048 + l0 + row) * DTR + col] =
                        acc[i][j][r];
                }
            }
    } else {
        // scan cols 32..63 -> sC[n-32][l]
#pragma unroll
        for (int i = 0; i < 2; ++i)
#pragma unroll
            for (int j = 0; j < 2; ++j) {
                int col = 16 * j + lm;
#pragma unroll
                for (int r = 0; r < 4; ++r)
                    sC[col][wm + 16 * i + lq * 4 + r] = acc[i][j][r];
            }
    }
    __syncthreads();
    {
        int nr = tid >> 3, ll = (tid & 7) * 8;
        float4 v0 = *(const float4*)&sC[nr][ll];
        float4 v1 = *(const float4*)&sC[nr][ll + 4];
        float* d = dblt + (size_t)(bB * 64 + 32 + nr) * LD + l0 + ll;
        *(float4*)d = v0; *(float4*)(d + 4) = v1;
    }
}

// ---------------- g3m: MFMA dlt_t = softplus(dbldt @ dtw + b)^T --------------
// M=4096(l), N=1024(e), K=32 -> single mfma step per tile.
__global__ __launch_bounds__(256)
void g3m_k(const float* __restrict__ dbldt2, const bf16* __restrict__ dtwT2,
           const float* __restrict__ dtb_f, const float* __restrict__ dtb_b,
           bf16* __restrict__ dltt2)
{
    __shared__ __align__(16) bf16 As[64][40];
    __shared__ __align__(16) bf16 Bs[64][32];
    __shared__ float sC[64][65];
    const int tid = threadIdx.x;
    const int dir = blockIdx.z;
    const float* Ap = dbldt2 + (size_t)dir * (2 * 2048 * DTR);
    const bf16* BT = dtwT2 + (size_t)dir * (1024 * DTR);
    const float* bias = dir ? dtb_b : dtb_f;
    bf16* dltt = dltt2 + (size_t)dir * ((size_t)MROWS * EDIM);
    const int bm = blockIdx.y * 64, bn = blockIdx.x * 64;
    const int bB = bm >> 11, l0 = bm & (LD - 1);
    const int wave = tid >> 6, lane = tid & 63;
    const int wm = (wave >> 1) * 32, wn = (wave & 1) * 32;
    const int lm = lane & 15, lq = lane >> 4;

    {
        int row = tid >> 2, c8 = (tid & 3) * 8;
        const float* p = Ap + (size_t)(bB * 2048 + l0 + row) * DTR + c8;
        float4 v0 = *(const float4*)p, v1 = *(const float4*)(p + 4);
        bf16x8 o;
        o[0]=(__bf16)v0.x; o[1]=(__bf16)v0.y; o[2]=(__bf16)v0.z; o[3]=(__bf16)v0.w;
        o[4]=(__bf16)v1.x; o[5]=(__bf16)v1.y; o[6]=(__bf16)v1.z; o[7]=(__bf16)v1.w;
        *(bf16x8*)&As[row][c8] = o;
    }
    glds16(BT + (size_t)(bn + wave * 16 + (lane >> 2)) * DTR + (lane & 3) * 8,
           &Bs[wave * 16][0]);
    __syncthreads();

    bf16x8 af[2], bfr[2];
#pragma unroll
    for (int i = 0; i < 2; ++i)
        af[i] = *(const bf16x8*)&As[wm + 16 * i + lm][lq * 8];
#pragma unroll
    for (int j = 0; j < 2; ++j)
        bfr[j] = *(const bf16x8*)&Bs[wn + 16 * j + lm][lq * 8];
    f32x4 acc[2][2] = {};
#pragma unroll
    for (int i = 0; i < 2; ++i)
#pragma unroll
        for (int j = 0; j < 2; ++j)
            acc[i][j] = __builtin_amdgcn_mfma_f32_16x16x32_bf16(
                af[i], bfr[j], acc[i][j], 0, 0, 0);

#pragma unroll
    for (int i = 0; i < 2; ++i)
#pragma unroll
        for (int j = 0; j < 2; ++j) {
            int col = wn + 16 * j + lm;
            float bv = bias[bn + col];
#pragma unroll
            for (int r = 0; r < 4; ++r) {
                int row = wm + 16 * i + lq * 4 + r;
                float v = acc[i][j][r] + bv;
                v = (v > 20.f) ? v : log1pf(__expf(v));
                sC[col][row] = v;
            }
        }
    __syncthreads();
    {
        int erow = tid >> 2, l16 = (tid & 3) * 16;
        bf16* d = dltt + ((size_t)bB * EDIM + bn + erow) * LD + l0 + l16;
#pragma unroll
        for (int h = 0; h < 2; ++h) {
            bf16x8 o;
#pragma unroll
            for (int j = 0; j < 8; ++j) o[j] = (__bf16)sC[erow][l16 + h * 8 + j];
            *(bf16x8*)(d + h * 8) = o;
        }
    }
}

// ---------------- scan6 dir-merged: 256 chunks x 8 steps, parallel scan ------
__global__ __launch_bounds__(256)
void scan6_k(bf16* __restrict__ xct2, const bf16* __restrict__ dltt2,
             const float* __restrict__ dblt2,
             const float* __restrict__ alog_f, const float* __restrict__ alog_b,
             const float* __restrict__ dp_f, const float* __restrict__ dp_b)
{
    __shared__ float sA[NST];
    __shared__ float sWp[NST][4];
    __shared__ float sWs[NST][4];
    const int gid = blockIdx.x;                 // 0..4095
    const int dir = gid >> 11;
    const int bb  = (gid >> 10) & 1;
    const int e   = gid & (EDIM - 1);
    const float* A_log = dir ? alog_b : alog_f;
    const float* Dp    = dir ? dp_b   : dp_f;
    bf16* xct = xct2 + (size_t)dir * ((size_t)MROWS * EDIM);
    const bf16* dltt = dltt2 + (size_t)dir * ((size_t)MROWS * EDIM);
    const float* bt = dblt2 + (size_t)dir * (2 * 64 * LD) + (size_t)bb * 64 * LD;
    const int tid = threadIdx.x;
    const int wave = tid >> 6, lane = tid & 63;
    const size_t baset = ((size_t)bb * EDIM + e) * LD;
    const int l0 = tid * 8;

    if (tid < NST) sA[tid] = -__expf(A_log[e * NST + tid]);

    float xv[8], dv[8], dx[8];
    {
        bf16x8 xr = *(const bf16x8*)(xct + baset + l0);
        bf16x8 dr = *(const bf16x8*)(dltt + baset + l0);
#pragma unroll
        for (int j = 0; j < 8; ++j) { xv[j] = (float)xr[j]; dv[j] = (float)dr[j]; }
    }
#pragma unroll
    for (int j = 0; j < 8; ++j) dx[j] = dv[j] * xv[j];
    __syncthreads();

    float y[8] = {};
    for (int n = 0; n < NST; ++n) {
        const float An = sA[n];
        const float* Bp = bt + (size_t)(DTR + n) * LD + l0;
        const float* Cp = bt + (size_t)(DTR + NST + n) * LD + l0;
        float4 b0 = *(const float4*)Bp, b1 = *(const float4*)(Bp + 4);
        float4 c0 = *(const float4*)Cp, c1 = *(const float4*)(Cp + 4);
        float Br[8] = {b0.x,b0.y,b0.z,b0.w, b1.x,b1.y,b1.z,b1.w};
        float Cr[8] = {c0.x,c0.y,c0.z,c0.w, c1.x,c1.y,c1.z,c1.w};

        float S[8], P[8];
        float h = 0.f, pr = 1.f;
#pragma unroll
        for (int l = 0; l < 8; ++l) {
            float a = __expf(dv[l] * An);
            pr *= a;
            h = fmaf(a, h, dx[l] * Br[l]);
            P[l] = pr; S[l] = h;
        }

        float p = pr, s = h;
#pragma unroll
        for (int d = 1; d < 64; d <<= 1) {
            float pp = __shfl_up(p, d, 64);
            float sp = __shfl_up(s, d, 64);
            if (lane >= d) { s = fmaf(sp, p, s); p *= pp; }
        }
        if (lane == 63) { sWp[n][wave] = p; sWs[n][wave] = s; }
        __syncthreads();
        float Hoff = 0.f;
#pragma unroll
        for (int w = 0; w < 3; ++w)
            if (w < wave) Hoff = fmaf(sWp[n][w], Hoff, sWs[n][w]);
        float pprev = __shfl_up(p, 1, 64);
        float sprev = __shfl_up(s, 1, 64);
        float H = (lane == 0) ? Hoff : fmaf(pprev, Hoff, sprev);

#pragma unroll
        for (int l = 0; l < 8; ++l)
            y[l] = fmaf(Cr[l], fmaf(P[l], H, S[l]), y[l]);
    }

    const float Dv = Dp[e];
    bf16x8 o;
#pragma unroll
    for (int l = 0; l < 8; ++l) o[l] = (__bf16)fmaf(xv[l], Dv, y[l]);
    *(bf16x8*)(xct + baset + l0) = o;
}

// ---------------- layernorm (bf16 in-place), dir0 rows only ------------------
__global__ __launch_bounds__(256)
void ln_k(bf16* __restrict__ m, const float* __restrict__ gg,
          const float* __restrict__ bb)
{
    int row = (blockIdx.x * 256 + threadIdx.x) >> 6;
    int lane = threadIdx.x & 63;
    bf16* r = m + (size_t)row * DMODEL;
    float v[8], s = 0.f, s2 = 0.f;
#pragma unroll
    for (int i = 0; i < 8; ++i) {
        v[i] = __bfloat162float(r[lane + 64 * i]);
        s += v[i]; s2 = fmaf(v[i], v[i], s2);
    }
#pragma unroll
    for (int off = 32; off >= 1; off >>= 1) {
        s  += __shfl_xor(s, off, 64);
        s2 += __shfl_xor(s2, off, 64);
    }
    float mu = s * (1.f / DMODEL);
    float var = s2 * (1.f / DMODEL) - mu * mu;
    float inv = rsqrtf(var + 1e-5f);
#pragma unroll
    for (int i = 0; i < 8; ++i)
        r[lane + 64 * i] = __float2bfloat16(
            (v[i] - mu) * inv * gg[lane + 64 * i] + bb[lane + 64 * i]);
}

__global__ void sentinel_k(float* __restrict__ o)
{
    int i = blockIdx.x * 256 + threadIdx.x;
    o[i] = 100.0f;
}

extern "C" void kernel_launch(void* const* d_in, const int* in_sizes, int n_in,
                              void* d_out, int out_size, void* d_ws, size_t ws_size,
                              hipStream_t stream)
{
    const float* x    = (const float*)d_in[0];
    const float* n1g  = (const float*)d_in[19];
    const float* n1b  = (const float*)d_in[20];
    const float* fw1  = (const float*)d_in[23];
    const float* fb1  = (const float*)d_in[24];
    const float* fw2  = (const float*)d_in[25];
    const float* fb2  = (const float*)d_in[26];
    float* out = (float*)d_out;

    const size_t MiB = 1024 * 1024;
    const size_t SZ_DM = (size_t)MROWS * DMODEL;
    if (ws_size < 49 * MiB) {
        sentinel_k<<<dim3(SZ_DM / 256), dim3(256), 0, stream>>>(out);
        return;
    }

    // ---- 48.4 MiB layout ----
    char* base = (char*)d_ws;
    bf16* fw1T  = (bf16*)base;                 // [1024][512]        1 MiB
    bf16* fw2T  = (bf16*)(base + 1 * MiB);     // [512][1024]        1 MiB
    bf16* outwT = (bf16*)(base + 2 * MiB);     // [2][512][1024]     2 MiB
    bf16* inwT  = (bf16*)(base + 4 * MiB);     // [2][2048][512]     4 MiB
    bf16* xbf   = (bf16*)(base + 8 * MiB);     // [4096][512]        4 MiB
    char* RA    = base + 12 * MiB;             // 16 MiB: xs2 -> dltt2 -> yrow2 -> ffh2
    bf16* xs2   = (bf16*)RA;                   // [2][4096][1024]
    bf16* dltt2 = (bf16*)RA;
    bf16* yrow2 = (bf16*)RA;
    bf16* ffh2  = (bf16*)RA;
    char* RB    = base + 28 * MiB;             // 16 MiB: xct2 -> mbf2
    bf16* xct2  = (bf16*)RB;                   // [2][2][1024][2048]
    bf16* mbf2  = (bf16*)RB;                   // [2][4096][512]
    float* dblt2 = (float*)(base + 44 * MiB);  // [2][2][64][2048]   2 MiB (rows 32..63 used)
    float* dbldt2 = (float*)(base + 46 * MiB); // [2][2][2048][32]   2 MiB
    bf16* xpT2  = (bf16*)(base + 48 * MiB);               // [2][64][1024]  256 KiB
    bf16* dtwT2 = (bf16*)(base + 48 * MiB + 256 * 1024);  // [2][1024][32]  128 KiB

    const float* inw_f  = (const float*)d_in[1];
    const float* cw_f   = (const float*)d_in[2];
    const float* cb_f   = (const float*)d_in[3];
    const float* xp_f   = (const float*)d_in[4];
    const float* dtw_f  = (const float*)d_in[5];
    const float* dtb_f  = (const float*)d_in[6];
    const float* alog_f = (const float*)d_in[7];
    const float* dp_f   = (const float*)d_in[8];
    const float* outw_f = (const float*)d_in[9];
    const float* inw_b  = (const float*)d_in[10];
    const float* cw_b   = (const float*)d_in[11];
    const float* cb_b   = (const float*)d_in[12];
    const float* xp_b   = (const float*)d_in[13];
    const float* dtw_b  = (const float*)d_in[14];
    const float* dtb_b  = (const float*)d_in[15];
    const float* alog_b = (const float*)d_in[16];
    const float* dp_b   = (const float*)d_in[17];
    const float* outw_b = (const float*)d_in[18];

    dim3 blk(256);
    const size_t U = (size_t)MROWS * EDIM;   // 4,194,304 elems

    // 1. prep: all transposes + xconv
    prep_k<<<dim3(6336), blk, 0, stream>>>(x, xbf, inw_f, inw_b, inwT,
                                           outw_f, outw_b, outwT,
                                           fw1, fw1T, fw2, fw2T,
                                           xp_f, xp_b, xpT2,
                                           dtw_f, dtw_b, dtwT2);
    // 2. G1: xs2[dir] = x(flip d1) @ in_w[:, :1024]   M=4096 N=1024 K=512
    bgemm3_k<128, 0, true, false><<<dim3(8, 32, 2), blk, 0, stream>>>(
        xbf, 0, DMODEL, inwT, (size_t)2048 * 512, DMODEL, nullptr,
        xs2, U, EDIM, nullptr, 0, nullptr, DMODEL);
    // 3. conv + silu + transpose
    conv2_k<<<dim3(16, 64, 2), blk, 0, stream>>>(xs2, cw_f, cb_f, cw_b, cb_b, xct2);
    // 4. G2 (MFMA): dblt rows 32..63 + dbldt row-major
    g2m_k<<<dim3(1, 64, 2), blk, 0, stream>>>(xct2, xpT2, dblt2, dbldt2);
    // 5. G3 (MFMA): dltt2 (over dead xs2)
    g3m_k<<<dim3(16, 64, 2), blk, 0, stream>>>(dbldt2, dtwT2, dtb_f, dtb_b, dltt2);
    // 6. scan (in-place over xct2)
    scan6_k<<<dim3(4096), blk, 0, stream>>>(xct2, dltt2, dblt2,
                                            alog_f, alog_b, dp_f, dp_b);
    // 7. zgate: yrow2 = silu(x @ inw_z) * y  (writes over dead dltt2)
    zgate_k<<<dim3(8, 64, 2), blk, 0, stream>>>(xbf, inwT, xct2, yrow2);
    // 8. G4: mbf2[dir] = y @ out_w   M=4096 N=512 K=1024
    bgemm3_k<64, 0, false, false><<<dim3(8, 32, 2), blk, 0, stream>>>(
        yrow2, U, EDIM, outwT, (size_t)512 * 1024, EDIM, nullptr,
        mbf2, SZ_DM, DMODEL, nullptr, 0, nullptr, EDIM);
    // 9. LN on dir0 half of mbf2 (in place)
    ln_k<<<dim3(MROWS / 4), blk, 0, stream>>>(mbf2, n1g, n1b);
    // 10. G5: ffh2[dir] = relu(m @ fw1 + fb1)   M=4096 N=1024 K=512
    bgemm3_k<128, 2, false, false><<<dim3(8, 32, 2), blk, 0, stream>>>(
        mbf2, SZ_DM, DMODEL, fw1T, 0, DMODEL, fb1,
        ffh2, U, DFF, nullptr, 0, nullptr, DMODEL);
    // 11. G6 fused (concat-K): out = ffh_f@fw2 + ffh_b@fw2 + 2*fb2 + m_f + m_b
    bgemm3_k<64, 5, false, true><<<dim3(8, 32, 1), blk, 0, stream>>>(
        ffh2, U, DFF, fw2T, 0, DFF, fb2,
        nullptr, 0, DMODEL, mbf2, SZ_DM, out, 2 * DFF);
}

// Round 5
// 367.601 us; speedup vs baseline: 1.1857x; 1.0125x over previous
//
#include <hip/hip_runtime.h>
#include <hip/hip_bf16.h>
#include <math.h>

// BiMambaEncoderLayer: B=2, L=2048, D_MODEL=512, ED=1024, N=16, DCONV=4,
// DT_RANK=32, D_FF=1024. f32 in/out.
// Round-20:
//  (a) scan6 -> scan8: structured-A fast path RETRY with the uniform branch
//      HOISTED out of the n-loop (two fully specialized loops). scan7's
//      regression was in-loop branches blocking exp pipelining, not the
//      mul-chain itself. Fast path: 8 exps + 15x8 muls vs 128 exps.
//      Generic fallback loop identical to scan6 -> correctness for any input.
//  (b) bgemm3: BK=32 -> BK=64. Halves barrier-drain count (the measured
//      2-phase critical path per m233); 32 MFMA per barrier pair. LDS 32KB
//      at BN=128. ds_read conflicts ignored (measured irrelevant here).
//  Everything else unchanged from round-19. 11 dispatches, 48.4 MiB ws.

#define BD 2
#define LD 2048
#define DMODEL 512
#define EDIM 1024
#define NST 16
#define DTR 32
#define DFF 1024
#define MROWS (BD*LD)   // 4096

typedef __hip_bfloat16 bf16;
typedef __bf16 bf16x8 __attribute__((ext_vector_type(8)));
typedef __bf16 bf16x4 __attribute__((ext_vector_type(4)));
typedef float  f32x4  __attribute__((ext_vector_type(4)));

__device__ __forceinline__ float sig_(float x) { return 1.f / (1.f + __expf(-x)); }

// async 16B global->LDS (wave-uniform LDS base, per-lane global addr)
__device__ __forceinline__ void glds16(const void* g, void* l)
{
    __builtin_amdgcn_global_load_lds(
        (const __attribute__((address_space(1))) void*)g,
        (__attribute__((address_space(3))) void*)l, 16, 0, 0);
}

// ---------------- prep: all weight transposes + x->bf16, one dispatch --------
// [0,2048) xconv | [2048,4096) inwT | [4096,5120) outwT | [5120,5632) fw1T |
// [5632,6144) fw2T | [6144,6272) xpT | [6272,6336) dtwT
__global__ __launch_bounds__(256)
void prep_k(const float* __restrict__ x, bf16* __restrict__ xbf,
            const float* __restrict__ inw_f, const float* __restrict__ inw_b,
            bf16* __restrict__ inwT,
            const float* __restrict__ outw_f, const float* __restrict__ outw_b,
            bf16* __restrict__ outwT,
            const float* __restrict__ fw1, bf16* __restrict__ fw1T,
            const float* __restrict__ fw2, bf16* __restrict__ fw2T,
            const float* __restrict__ xp_f, const float* __restrict__ xp_b,
            bf16* __restrict__ xpT,
            const float* __restrict__ dtw_f, const float* __restrict__ dtw_b,
            bf16* __restrict__ dtwT)
{
    const int bid = blockIdx.x, tid = threadIdx.x;
    if (bid < 2048) {
        size_t i = (size_t)bid * 1024 + tid * 4;
        float4 v = *(const float4*)(x + i);
        bf16* o = xbf + i;
        o[0] = __float2bfloat16(v.x); o[1] = __float2bfloat16(v.y);
        o[2] = __float2bfloat16(v.z); o[3] = __float2bfloat16(v.w);
        return;
    }
    const float* W; bf16* WT; int R, C, cx, ry;
    if (bid < 4096) {
        int d = (bid - 2048) >> 10, t = (bid - 2048) & 1023;
        W = d ? inw_b : inw_f; WT = inwT + (size_t)d * 2048 * 512;
        R = 512; C = 2048; cx = t & 63; ry = t >> 6;
    } else if (bid < 5120) {
        int d = (bid - 4096) >> 9, t = (bid - 4096) & 511;
        W = d ? outw_b : outw_f; WT = outwT + (size_t)d * 512 * 1024;
        R = 1024; C = 512; cx = t & 15; ry = t >> 4;
    } else if (bid < 5632) {
        int t = bid - 5120; W = fw1; WT = fw1T; R = 512; C = 1024;
        cx = t & 31; ry = t >> 5;
    } else if (bid < 6144) {
        int t = bid - 5632; W = fw2; WT = fw2T; R = 1024; C = 512;
        cx = t & 15; ry = t >> 4;
    } else if (bid < 6272) {
        int d = (bid - 6144) >> 6, t = (bid - 6144) & 63;
        W = d ? xp_b : xp_f; WT = xpT + (size_t)d * 64 * 1024;
        R = 1024; C = 64; cx = t & 1; ry = t >> 1;
    } else {
        int d = (bid - 6272) >> 5, t = (bid - 6272) & 31;
        W = d ? dtw_b : dtw_f; WT = dtwT + (size_t)d * 1024 * DTR;
        R = 32; C = 1024; cx = t; ry = 0;
    }
    __shared__ float tt[32][33];
    const int c0 = cx * 32, r0 = ry * 32;
    const int col = tid & 31, rr = tid >> 5;
#pragma unroll
    for (int p = 0; p < 4; ++p)
        tt[p * 8 + rr][col] = W[(size_t)(r0 + p * 8 + rr) * C + c0 + col];
    __syncthreads();
#pragma unroll
    for (int p = 0; p < 4; ++p)
        WT[(size_t)(c0 + p * 8 + rr) * R + r0 + col] =
            __float2bfloat16(tt[col][p * 8 + rr]);
}

// ---------------- bgemm3: 128xBN MFMA GEMM, BK=64, global_load_lds ----------
template<int BN, int MODE, bool FLIPD1, bool CATK>
__global__ __launch_bounds__(256)
void bgemm3_k(const bf16* __restrict__ A, size_t Astr, int lda,
              const bf16* __restrict__ BT, size_t Bstr, int ldb,
              const float* __restrict__ bias,
              bf16* __restrict__ Cb, size_t Cstr, int ldc,
              const bf16* __restrict__ mp, size_t mpStr,
              float* __restrict__ outp, int K)
{
    constexpr int BM = 128, BK = 64;
    constexpr int FRm = 4, FRn = BN / 32;
    constexpr int KH = DFF;   // concat-K half length (1024)
    __shared__ __align__(16) bf16 As[BM][BK];
    __shared__ __align__(16) bf16 Bs[BN][BK];
    const int tid = threadIdx.x;
    const int dir = blockIdx.z;
    const bool flip = FLIPD1 && (dir == 1);
    const bf16* Ad = A + (CATK ? (size_t)0 : (size_t)dir * Astr);
    const bf16* Bd = BT + (size_t)dir * Bstr;
    const int bm = blockIdx.y * BM, bn = blockIdx.x * BN;
    const int wave = tid >> 6, lane = tid & 63;
    const int wm = (wave >> 1) * 64, wn = (wave & 1) * (BN / 2);
    const int lm = lane & 15, lq = lane >> 4;
    const int lrow = lane >> 3, lcol = (lane & 7) * 8;   // 8 rows x 128B / wave
    f32x4 acc[FRm][FRn] = {};

    for (int k0 = 0; k0 < K; k0 += BK) {
        const bf16* Ab = Ad;
        int ka = k0;
        if (CATK && k0 >= KH) { Ab = A + Astr; ka = k0 - KH; }
        const int kb = CATK ? (k0 & (KH - 1)) : k0;
        // stage A tile (128x64 bf16 = 16KB): 4 rounds x 4 waves x 8 rows
#pragma unroll
        for (int c = 0; c < 4; ++c) {
            int row = c * 32 + wave * 8 + lrow;
            int gm = bm + row;
            if (flip) gm = (gm & ~(LD - 1)) + (LD - 1 - (gm & (LD - 1)));
            glds16(Ab + (size_t)gm * lda + ka + lcol,
                   &As[c * 32 + wave * 8][0]);
        }
        // stage B tile (BNx64): BN/32 rounds
#pragma unroll
        for (int c = 0; c < BN / 32; ++c) {
            int row = c * 32 + wave * 8 + lrow;
            glds16(Bd + (size_t)(bn + row) * ldb + kb + lcol,
                   &Bs[c * 32 + wave * 8][0]);
        }
        __syncthreads();   // drains vmcnt -> staging complete

#pragma unroll
        for (int kh = 0; kh < 2; ++kh) {
            bf16x8 af[FRm], bfr[FRn];
#pragma unroll
            for (int i = 0; i < FRm; ++i)
                af[i] = *(const bf16x8*)&As[wm + 16 * i + lm][kh * 32 + lq * 8];
#pragma unroll
            for (int j = 0; j < FRn; ++j)
                bfr[j] = *(const bf16x8*)&Bs[wn + 16 * j + lm][kh * 32 + lq * 8];
#pragma unroll
            for (int i = 0; i < FRm; ++i)
#pragma unroll
                for (int j = 0; j < FRn; ++j)
                    acc[i][j] = __builtin_amdgcn_mfma_f32_16x16x32_bf16(
                        af[i], bfr[j], acc[i][j], 0, 0, 0);
        }
        __syncthreads();
    }

    bf16* Cd = (MODE == 5) ? nullptr : Cb + (size_t)dir * Cstr;
#pragma unroll
    for (int i = 0; i < FRm; ++i) {
#pragma unroll
        for (int j = 0; j < FRn; ++j) {
            int col = bn + wn + 16 * j + lm;
            float bv = (MODE == 2) ? bias[col]
                     : (MODE == 5) ? 2.f * bias[col] : 0.f;
#pragma unroll
            for (int r = 0; r < 4; ++r) {
                int row = bm + wm + 16 * i + lq * 4 + r;
                float v = acc[i][j][r] + bv;
                size_t idx = (size_t)row * ldc + col;
                if (MODE == 0)      Cd[idx] = __float2bfloat16(v);
                else if (MODE == 2) Cd[idx] = __float2bfloat16(fmaxf(v, 0.f));
                else {
                    float m2 = __bfloat162float(mp[idx])
                             + __bfloat162float(mp[mpStr + idx]);
                    outp[idx] = v + m2;
                }
            }
        }
    }
}

// ---------------- zgate: yrow = silu(x(flip?) @ inw_z) * y2t^T ---------------
__global__ __launch_bounds__(256)
void zgate_k(const bf16* __restrict__ xbf, const bf16* __restrict__ inwT,
             const bf16* __restrict__ y2t_all, bf16* __restrict__ yrow_all)
{
    __shared__ __align__(16) bf16 As[64][40];
    __shared__ __align__(16) bf16 Bs[128][40];
    __shared__ __bf16 sy[64][130];
    const int tid = threadIdx.x;
    const int dir = blockIdx.z;
    const bf16* Bd = inwT + (size_t)dir * (2048 * 512) + (size_t)1024 * 512;
    const bf16* y2t = y2t_all + (size_t)dir * ((size_t)MROWS * EDIM);
    bf16* yrow = yrow_all + (size_t)dir * ((size_t)MROWS * EDIM);
    const int bm = blockIdx.y * 64, bn = blockIdx.x * 128;
    const int wave = tid >> 6, lane = tid & 63;
    const int wm = (wave >> 1) * 32, wn = (wave & 1) * 64;
    const int lm = lane & 15, lq = lane >> 4;
    f32x4 acc[2][4] = {};

    for (int k0 = 0; k0 < 512; k0 += 32) {
        {
            int row = tid >> 2, col = (tid & 3) * 8;
            int gm = bm + row;
            if (dir == 1) gm = (gm & ~(LD - 1)) + (LD - 1 - (gm & (LD - 1)));
            *(bf16x8*)&As[row][col] =
                *(const bf16x8*)(xbf + (size_t)gm * 512 + k0 + col);
        }
#pragma unroll
        for (int p = 0; p < 2; ++p) {
            int row = p * 64 + (tid >> 2), col = (tid & 3) * 8;
            *(bf16x8*)&Bs[row][col] =
                *(const bf16x8*)(Bd + (size_t)(bn + row) * 512 + k0 + col);
        }
        __syncthreads();
        bf16x8 af[2], bfr[4];
#pragma unroll
        for (int i = 0; i < 2; ++i)
            af[i] = *(const bf16x8*)&As[wm + 16 * i + lm][lq * 8];
#pragma unroll
        for (int j = 0; j < 4; ++j)
            bfr[j] = *(const bf16x8*)&Bs[wn + 16 * j + lm][lq * 8];
#pragma unroll
        for (int i = 0; i < 2; ++i)
#pragma unroll
            for (int j = 0; j < 4; ++j)
                acc[i][j] = __builtin_amdgcn_mfma_f32_16x16x32_bf16(
                    af[i], bfr[j], acc[i][j], 0, 0, 0);
        __syncthreads();
    }

    {
        const int b = bm >> 11, l0 = bm & (LD - 1);
        int e = tid >> 1, lh = (tid & 1) * 32;
        const bf16* yp = y2t + ((size_t)b * EDIM + bn + e) * LD + l0 + lh;
#pragma unroll
        for (int i = 0; i < 4; ++i) {
            bf16x8 v = *(const bf16x8*)(yp + i * 8);
#pragma unroll
            for (int j = 0; j < 8; ++j) sy[lh + i * 8 + j][e] = v[j];
        }
    }
    __syncthreads();
#pragma unroll
    for (int i = 0; i < 2; ++i) {
#pragma unroll
        for (int j = 0; j < 4; ++j) {
            int col = bn + wn + 16 * j + lm;
#pragma unroll
            for (int r = 0; r < 4; ++r) {
                int row = bm + wm + 16 * i + lq * 4 + r;
                float z = acc[i][j][r];
                float g = z * sig_(z);
                float y = (float)sy[(row - bm)][col - bn];
                yrow[(size_t)row * EDIM + col] = __float2bfloat16(g * y);
            }
        }
    }
}

// ---------------- conv(4)+bias+silu+transpose, dir-merged, vectorized --------
__global__ __launch_bounds__(256)
void conv2_k(const bf16* __restrict__ xs2,
             const float* __restrict__ cw_f, const float* __restrict__ cb_f,
             const float* __restrict__ cw_b, const float* __restrict__ cb_b,
             bf16* __restrict__ xct2)
{
    __shared__ float sxs[67][65];
    __shared__ float sout[64][65];
    const int tid = threadIdx.x;
    const int dir = blockIdx.z;
    const bf16* xs = xs2 + (size_t)dir * ((size_t)MROWS * EDIM);
    const float* w  = dir ? cw_b : cw_f;
    const float* cb = dir ? cb_b : cb_f;
    bf16* xct = xct2 + (size_t)dir * ((size_t)MROWS * EDIM);
    const int e0 = blockIdx.x * 64;
    const int bl0 = blockIdx.y * 64;
    const int lloc0 = bl0 & (LD - 1);
    const int b = bl0 >> 11;
    {
        int c8 = (tid & 7) * 8;
#pragma unroll
        for (int i = 0; i < 3; ++i) {
            int hr = i * 32 + (tid >> 3);
            if (hr < 67) {
                int lr = lloc0 + hr - 3;
                if (lr >= 0) {
                    bf16x8 v = *(const bf16x8*)(xs +
                        (size_t)(bl0 + hr - 3) * EDIM + e0 + c8);
#pragma unroll
                    for (int j = 0; j < 8; ++j) sxs[hr][c8 + j] = (float)v[j];
                } else {
#pragma unroll
                    for (int j = 0; j < 8; ++j) sxs[hr][c8 + j] = 0.f;
                }
            }
        }
    }
    __syncthreads();
    {
        int lr4 = tid >> 6, e = tid & 63;
        float w0 = w[(e0 + e) * 4 + 0], w1 = w[(e0 + e) * 4 + 1];
        float w2 = w[(e0 + e) * 4 + 2], w3 = w[(e0 + e) * 4 + 3];
        float cbv = cb[e0 + e];
#pragma unroll
        for (int i = 0; i < 16; ++i) {
            int lr = i * 4 + lr4;
            float acc = cbv;
            acc = fmaf(sxs[lr + 0][e], w0, acc);
            acc = fmaf(sxs[lr + 1][e], w1, acc);
            acc = fmaf(sxs[lr + 2][e], w2, acc);
            acc = fmaf(sxs[lr + 3][e], w3, acc);
            sout[e][lr] = acc * sig_(acc);
        }
    }
    __syncthreads();
    {
        int l8 = (tid & 7) * 8;
#pragma unroll
        for (int i = 0; i < 2; ++i) {
            int er = i * 32 + (tid >> 3);
            bf16x8 o;
#pragma unroll
            for (int j = 0; j < 8; ++j) o[j] = (__bf16)sout[er][l8 + j];
            *(bf16x8*)(xct + ((size_t)b * EDIM + e0 + er) * LD + lloc0 + l8) = o;
        }
    }
}

// ---------------- g2m: MFMA dbl = xc @ xproj (dt rows row-major) -------------
__global__ __launch_bounds__(256)
void g2m_k(const bf16* __restrict__ xct2, const bf16* __restrict__ xpT2,
           float* __restrict__ dblt2, float* __restrict__ dbldt2)
{
    __shared__ float As[64][33];            // [l][e] transposed, <=2-way banks
    __shared__ __align__(16) bf16 Bs[64][32];
    __shared__ float sC[32][65];            // n-rows 32..63 staging
    const int tid = threadIdx.x;
    const int dir = blockIdx.z;
    const bf16* xct = xct2 + (size_t)dir * ((size_t)MROWS * EDIM);
    const bf16* xpT = xpT2 + (size_t)dir * (64 * 1024);
    float* dblt = dblt2 + (size_t)dir * (2 * 64 * LD);
    float* dbldt = dbldt2 + (size_t)dir * (2 * 2048 * DTR);
    const int bm = blockIdx.y * 64;
    const int bB = bm >> 11, l0 = bm & (LD - 1);
    const int wave = tid >> 6, lane = tid & 63;
    const int wm = (wave >> 1) * 32, wn = (wave & 1) * 32;
    const int lm = lane & 15, lq = lane >> 4;
    const int er = tid >> 3, l8 = (tid & 7) * 8;   // A-stage coords
    f32x4 acc[2][2] = {};

    for (int k0 = 0; k0 < EDIM; k0 += 32) {
        glds16(xpT + (size_t)(wave * 16 + (lane >> 2)) * 1024 + k0 + (lane & 3) * 8,
               &Bs[wave * 16][0]);
        {
            bf16x8 v = *(const bf16x8*)(xct +
                ((size_t)bB * EDIM + k0 + er) * LD + l0 + l8);
#pragma unroll
            for (int j = 0; j < 8; ++j) As[l8 + j][er] = (float)v[j];
        }
        __syncthreads();
        bf16x8 af[2], bfr[2];
#pragma unroll
        for (int i = 0; i < 2; ++i) {
            int row = wm + 16 * i + lm;
#pragma unroll
            for (int j = 0; j < 8; ++j) af[i][j] = (__bf16)As[row][lq * 8 + j];
        }
#pragma unroll
        for (int j = 0; j < 2; ++j)
            bfr[j] = *(const bf16x8*)&Bs[wn + 16 * j + lm][lq * 8];
#pragma unroll
        for (int i = 0; i < 2; ++i)
#pragma unroll
            for (int j = 0; j < 2; ++j)
                acc[i][j] = __builtin_amdgcn_mfma_f32_16x16x32_bf16(
                    af[i], bfr[j], acc[i][j], 0, 0, 0);
        __syncthreads();
    }
    if (wn == 0) {
#pragma unroll
        for (int i = 0; i < 2; ++i)
#pragma unroll
            for (int j = 0; j < 2; ++j) {
                int col = 16 * j + lm;
#pragma unroll
                for (int r = 0; r < 4; ++r) {
                    int row = wm + 16 * i + lq * 4 + r;
                    dbldt[(size_t)(bB * 2048 + l0 + row) * DTR + col] =
                        acc[i][j][r];
                }
            }
    } else {
#pragma unroll
        for (int i = 0; i < 2; ++i)
#pragma unroll
            for (int j = 0; j < 2; ++j) {
                int col = 16 * j + lm;
#pragma unroll
                for (int r = 0; r < 4; ++r)
                    sC[col][wm + 16 * i + lq * 4 + r] = acc[i][j][r];
            }
    }
    __syncthreads();
    {
        int nr = tid >> 3, ll = (tid & 7) * 8;
        float4 v0 = *(const float4*)&sC[nr][ll];
        float4 v1 = *(const float4*)&sC[nr][ll + 4];
        float* d = dblt + (size_t)(bB * 64 + 32 + nr) * LD + l0 + ll;
        *(float4*)d = v0; *(float4*)(d + 4) = v1;
    }
}

// ---------------- g3m: MFMA dlt_t = softplus(dbldt @ dtw + b)^T --------------
__global__ __launch_bounds__(256)
void g3m_k(const float* __restrict__ dbldt2, const bf16* __restrict__ dtwT2,
           const float* __restrict__ dtb_f, const float* __restrict__ dtb_b,
           bf16* __restrict__ dltt2)
{
    __shared__ __align__(16) bf16 As[64][40];
    __shared__ __align__(16) bf16 Bs[64][32];
    __shared__ float sC[64][65];
    const int tid = threadIdx.x;
    const int dir = blockIdx.z;
    const float* Ap = dbldt2 + (size_t)dir * (2 * 2048 * DTR);
    const bf16* BT = dtwT2 + (size_t)dir * (1024 * DTR);
    const float* bias = dir ? dtb_b : dtb_f;
    bf16* dltt = dltt2 + (size_t)dir * ((size_t)MROWS * EDIM);
    const int bm = blockIdx.y * 64, bn = blockIdx.x * 64;
    const int bB = bm >> 11, l0 = bm & (LD - 1);
    const int wave = tid >> 6, lane = tid & 63;
    const int wm = (wave >> 1) * 32, wn = (wave & 1) * 32;
    const int lm = lane & 15, lq = lane >> 4;

    {
        int row = tid >> 2, c8 = (tid & 3) * 8;
        const float* p = Ap + (size_t)(bB * 2048 + l0 + row) * DTR + c8;
        float4 v0 = *(const float4*)p, v1 = *(const float4*)(p + 4);
        bf16x8 o;
        o[0]=(__bf16)v0.x; o[1]=(__bf16)v0.y; o[2]=(__bf16)v0.z; o[3]=(__bf16)v0.w;
        o[4]=(__bf16)v1.x; o[5]=(__bf16)v1.y; o[6]=(__bf16)v1.z; o[7]=(__bf16)v1.w;
        *(bf16x8*)&As[row][c8] = o;
    }
    glds16(BT + (size_t)(bn + wave * 16 + (lane >> 2)) * DTR + (lane & 3) * 8,
           &Bs[wave * 16][0]);
    __syncthreads();

    bf16x8 af[2], bfr[2];
#pragma unroll
    for (int i = 0; i < 2; ++i)
        af[i] = *(const bf16x8*)&As[wm + 16 * i + lm][lq * 8];
#pragma unroll
    for (int j = 0; j < 2; ++j)
        bfr[j] = *(const bf16x8*)&Bs[wn + 16 * j + lm][lq * 8];
    f32x4 acc[2][2] = {};
#pragma unroll
    for (int i = 0; i < 2; ++i)
#pragma unroll
        for (int j = 0; j < 2; ++j)
            acc[i][j] = __builtin_amdgcn_mfma_f32_16x16x32_bf16(
                af[i], bfr[j], acc[i][j], 0, 0, 0);

#pragma unroll
    for (int i = 0; i < 2; ++i)
#pragma unroll
        for (int j = 0; j < 2; ++j) {
            int col = wn + 16 * j + lm;
            float bv = bias[bn + col];
#pragma unroll
            for (int r = 0; r < 4; ++r) {
                int row = wm + 16 * i + lq * 4 + r;
                float v = acc[i][j][r] + bv;
                v = (v > 20.f) ? v : log1pf(__expf(v));
                sC[col][row] = v;
            }
        }
    __syncthreads();
    {
        int erow = tid >> 2, l16 = (tid & 3) * 16;
        bf16* d = dltt + ((size_t)bB * EDIM + bn + erow) * LD + l0 + l16;
#pragma unroll
        for (int h = 0; h < 2; ++h) {
            bf16x8 o;
#pragma unroll
            for (int j = 0; j < 8; ++j) o[j] = (__bf16)sC[erow][l16 + h * 8 + j];
            *(bf16x8*)(d + h * 8) = o;
        }
    }
}

// ---------------- scan8: parallel scan, structured-A dual loop ---------------
// Per block: one (dir, batch, e) channel; 256 threads x 8-step chunks.
// Affine partials (S,P) in registers; Kogge-Stone affine scan + 4-entry LDS
// cross-wave compose. The structured-A check (A_n == A_0*(n+1), true for
// this model) is hoisted: two fully specialized loops, so the fast path's
// scheduler sees straight-line code (scan7's in-loop branches caused stalls).
__global__ __launch_bounds__(256)
void scan8_k(bf16* __restrict__ xct2, const bf16* __restrict__ dltt2,
             const float* __restrict__ dblt2,
             const float* __restrict__ alog_f, const float* __restrict__ alog_b,
             const float* __restrict__ dp_f, const float* __restrict__ dp_b)
{
    __shared__ float sA[NST];
    __shared__ float sWp[NST][4];
    __shared__ float sWs[NST][4];
    const int gid = blockIdx.x;                 // 0..4095
    const int dir = gid >> 11;
    const int bb  = (gid >> 10) & 1;
    const int e   = gid & (EDIM - 1);
    const float* A_log = dir ? alog_b : alog_f;
    const float* Dp    = dir ? dp_b   : dp_f;
    bf16* xct = xct2 + (size_t)dir * ((size_t)MROWS * EDIM);
    const bf16* dltt = dltt2 + (size_t)dir * ((size_t)MROWS * EDIM);
    const float* bt = dblt2 + (size_t)dir * (2 * 64 * LD) + (size_t)bb * 64 * LD;
    const int tid = threadIdx.x;
    const int wave = tid >> 6, lane = tid & 63;
    const size_t baset = ((size_t)bb * EDIM + e) * LD;
    const int l0 = tid * 8;

    if (tid < NST) sA[tid] = -__expf(A_log[e * NST + tid]);

    float xv[8], dv[8], dx[8];
    {
        bf16x8 xr = *(const bf16x8*)(xct + baset + l0);
        bf16x8 dr = *(const bf16x8*)(dltt + baset + l0);
#pragma unroll
        for (int j = 0; j < 8; ++j) { xv[j] = (float)xr[j]; dv[j] = (float)dr[j]; }
    }
#pragma unroll
    for (int j = 0; j < 8; ++j) dx[j] = dv[j] * xv[j];
    __syncthreads();

    // structured-A detection (wave-uniform branch; fallback = exact scan6)
    const float A1 = sA[0];
    bool linA = true;
#pragma unroll
    for (int n = 1; n < NST; ++n)
        linA = linA && (fabsf(sA[n] - A1 * (float)(n + 1))
                        <= 1e-4f * (float)(n + 1) * fabsf(A1) + 1e-6f);

    float y[8] = {};
    if (linA) {
        float q[8], dA[8];
#pragma unroll
        for (int l = 0; l < 8; ++l) { q[l] = __expf(A1 * dv[l]); dA[l] = q[l]; }
        for (int n = 0; n < NST; ++n) {
            const float* Bp = bt + (size_t)(DTR + n) * LD + l0;
            const float* Cp = bt + (size_t)(DTR + NST + n) * LD + l0;
            float4 b0 = *(const float4*)Bp, b1 = *(const float4*)(Bp + 4);
            float4 c0 = *(const float4*)Cp, c1 = *(const float4*)(Cp + 4);
            float Br[8] = {b0.x,b0.y,b0.z,b0.w, b1.x,b1.y,b1.z,b1.w};
            float Cr[8] = {c0.x,c0.y,c0.z,c0.w, c1.x,c1.y,c1.z,c1.w};

            float S[8], P[8];
            float h = 0.f, pr = 1.f;
#pragma unroll
            for (int l = 0; l < 8; ++l) {
                float a = dA[l];
                pr *= a;
                h = fmaf(a, h, dx[l] * Br[l]);
                P[l] = pr; S[l] = h;
            }
            float p = pr, s = h;
#pragma unroll
            for (int d = 1; d < 64; d <<= 1) {
                float pp = __shfl_up(p, d, 64);
                float sp = __shfl_up(s, d, 64);
                if (lane >= d) { s = fmaf(sp, p, s); p *= pp; }
            }
            if (lane == 63) { sWp[n][wave] = p; sWs[n][wave] = s; }
            __syncthreads();
            float Hoff = 0.f;
#pragma unroll
            for (int w = 0; w < 3; ++w)
                if (w < wave) Hoff = fmaf(sWp[n][w], Hoff, sWs[n][w]);
            float pprev = __shfl_up(p, 1, 64);
            float sprev = __shfl_up(s, 1, 64);
            float H = (lane == 0) ? Hoff : fmaf(pprev, Hoff, sprev);
#pragma unroll
            for (int l = 0; l < 8; ++l)
                y[l] = fmaf(Cr[l], fmaf(P[l], H, S[l]), y[l]);
#pragma unroll
            for (int l = 0; l < 8; ++l) dA[l] *= q[l];
        }
    } else {
        for (int n = 0; n < NST; ++n) {
            const float An = sA[n];
            const float* Bp = bt + (size_t)(DTR + n) * LD + l0;
            const float* Cp = bt + (size_t)(DTR + NST + n) * LD + l0;
            float4 b0 = *(const float4*)Bp, b1 = *(const float4*)(Bp + 4);
            float4 c0 = *(const float4*)Cp, c1 = *(const float4*)(Cp + 4);
            float Br[8] = {b0.x,b0.y,b0.z,b0.w, b1.x,b1.y,b1.z,b1.w};
            float Cr[8] = {c0.x,c0.y,c0.z,c0.w, c1.x,c1.y,c1.z,c1.w};

            float S[8], P[8];
            float h = 0.f, pr = 1.f;
#pragma unroll
            for (int l = 0; l < 8; ++l) {
                float a = __expf(dv[l] * An);
                pr *= a;
                h = fmaf(a, h, dx[l] * Br[l]);
                P[l] = pr; S[l] = h;
            }
            float p = pr, s = h;
#pragma unroll
            for (int d = 1; d < 64; d <<= 1) {
                float pp = __shfl_up(p, d, 64);
                float sp = __shfl_up(s, d, 64);
                if (lane >= d) { s = fmaf(sp, p, s); p *= pp; }
            }
            if (lane == 63) { sWp[n][wave] = p; sWs[n][wave] = s; }
            __syncthreads();
            float Hoff = 0.f;
#pragma unroll
            for (int w = 0; w < 3; ++w)
                if (w < wave) Hoff = fmaf(sWp[n][w], Hoff, sWs[n][w]);
            float pprev = __shfl_up(p, 1, 64);
            float sprev = __shfl_up(s, 1, 64);
            float H = (lane == 0) ? Hoff : fmaf(pprev, Hoff, sprev);
#pragma unroll
            for (int l = 0; l < 8; ++l)
                y[l] = fmaf(Cr[l], fmaf(P[l], H, S[l]), y[l]);
        }
    }

    const float Dv = Dp[e];
    bf16x8 o;
#pragma unroll
    for (int l = 0; l < 8; ++l) o[l] = (__bf16)fmaf(xv[l], Dv, y[l]);
    *(bf16x8*)(xct + baset + l0) = o;
}

// ---------------- layernorm (bf16 in-place), dir0 rows only ------------------
__global__ __launch_bounds__(256)
void ln_k(bf16* __restrict__ m, const float* __restrict__ gg,
          const float* __restrict__ bb)
{
    int row = (blockIdx.x * 256 + threadIdx.x) >> 6;
    int lane = threadIdx.x & 63;
    bf16* r = m + (size_t)row * DMODEL;
    float v[8], s = 0.f, s2 = 0.f;
#pragma unroll
    for (int i = 0; i < 8; ++i) {
        v[i] = __bfloat162float(r[lane + 64 * i]);
        s += v[i]; s2 = fmaf(v[i], v[i], s2);
    }
#pragma unroll
    for (int off = 32; off >= 1; off >>= 1) {
        s  += __shfl_xor(s, off, 64);
        s2 += __shfl_xor(s2, off, 64);
    }
    float mu = s * (1.f / DMODEL);
    float var = s2 * (1.f / DMODEL) - mu * mu;
    float inv = rsqrtf(var + 1e-5f);
#pragma unroll
    for (int i = 0; i < 8; ++i)
        r[lane + 64 * i] = __float2bfloat16(
            (v[i] - mu) * inv * gg[lane + 64 * i] + bb[lane + 64 * i]);
}

__global__ void sentinel_k(float* __restrict__ o)
{
    int i = blockIdx.x * 256 + threadIdx.x;
    o[i] = 100.0f;
}

extern "C" void kernel_launch(void* const* d_in, const int* in_sizes, int n_in,
                              void* d_out, int out_size, void* d_ws, size_t ws_size,
                              hipStream_t stream)
{
    const float* x    = (const float*)d_in[0];
    const float* n1g  = (const float*)d_in[19];
    const float* n1b  = (const float*)d_in[20];
    const float* fw1  = (const float*)d_in[23];
    const float* fb1  = (const float*)d_in[24];
    const float* fw2  = (const float*)d_in[25];
    const float* fb2  = (const float*)d_in[26];
    float* out = (float*)d_out;

    const size_t MiB = 1024 * 1024;
    const size_t SZ_DM = (size_t)MROWS * DMODEL;
    if (ws_size < 49 * MiB) {
        sentinel_k<<<dim3(SZ_DM / 256), dim3(256), 0, stream>>>(out);
        return;
    }

    // ---- 48.4 MiB layout ----
    char* base = (char*)d_ws;
    bf16* fw1T  = (bf16*)base;                 // [1024][512]        1 MiB
    bf16* fw2T  = (bf16*)(base + 1 * MiB);     // [512][1024]        1 MiB
    bf16* outwT = (bf16*)(base + 2 * MiB);     // [2][512][1024]     2 MiB
    bf16* inwT  = (bf16*)(base + 4 * MiB);     // [2][2048][512]     4 MiB
    bf16* xbf   = (bf16*)(base + 8 * MiB);     // [4096][512]        4 MiB
    char* RA    = base + 12 * MiB;             // 16 MiB: xs2 -> dltt2 -> yrow2 -> ffh2
    bf16* xs2   = (bf16*)RA;                   // [2][4096][1024]
    bf16* dltt2 = (bf16*)RA;
    bf16* yrow2 = (bf16*)RA;
    bf16* ffh2  = (bf16*)RA;
    char* RB    = base + 28 * MiB;             // 16 MiB: xct2 -> mbf2
    bf16* xct2  = (bf16*)RB;                   // [2][2][1024][2048]
    bf16* mbf2  = (bf16*)RB;                   // [2][4096][512]
    float* dblt2 = (float*)(base + 44 * MiB);  // [2][2][64][2048]   2 MiB (rows 32..63 used)
    float* dbldt2 = (float*)(base + 46 * MiB); // [2][2][2048][32]   2 MiB
    bf16* xpT2  = (bf16*)(base + 48 * MiB);               // [2][64][1024]  256 KiB
    bf16* dtwT2 = (bf16*)(base + 48 * MiB + 256 * 1024);  // [2][1024][32]  128 KiB

    const float* inw_f  = (const float*)d_in[1];
    const float* cw_f   = (const float*)d_in[2];
    const float* cb_f   = (const float*)d_in[3];
    const float* xp_f   = (const float*)d_in[4];
    const float* dtw_f  = (const float*)d_in[5];
    const float* dtb_f  = (const float*)d_in[6];
    const float* alog_f = (const float*)d_in[7];
    const float* dp_f   = (const float*)d_in[8];
    const float* outw_f = (const float*)d_in[9];
    const float* inw_b  = (const float*)d_in[10];
    const float* cw_b   = (const float*)d_in[11];
    const float* cb_b   = (const float*)d_in[12];
    const float* xp_b   = (const float*)d_in[13];
    const float* dtw_b  = (const float*)d_in[14];
    const float* dtb_b  = (const float*)d_in[15];
    const float* alog_b = (const float*)d_in[16];
    const float* dp_b   = (const float*)d_in[17];
    const float* outw_b = (const float*)d_in[18];

    dim3 blk(256);
    const size_t U = (size_t)MROWS * EDIM;   // 4,194,304 elems

    // 1. prep: all transposes + xconv
    prep_k<<<dim3(6336), blk, 0, stream>>>(x, xbf, inw_f, inw_b, inwT,
                                           outw_f, outw_b, outwT,
                                           fw1, fw1T, fw2, fw2T,
                                           xp_f, xp_b, xpT2,
                                           dtw_f, dtw_b, dtwT2);
    // 2. G1: xs2[dir] = x(flip d1) @ in_w[:, :1024]   M=4096 N=1024 K=512
    bgemm3_k<128, 0, true, false><<<dim3(8, 32, 2), blk, 0, stream>>>(
        xbf, 0, DMODEL, inwT, (size_t)2048 * 512, DMODEL, nullptr,
        xs2, U, EDIM, nullptr, 0, nullptr, DMODEL);
    // 3. conv + silu + transpose
    conv2_k<<<dim3(16, 64, 2), blk, 0, stream>>>(xs2, cw_f, cb_f, cw_b, cb_b, xct2);
    // 4. G2 (MFMA): dblt rows 32..63 + dbldt row-major
    g2m_k<<<dim3(1, 64, 2), blk, 0, stream>>>(xct2, xpT2, dblt2, dbldt2);
    // 5. G3 (MFMA): dltt2 (over dead xs2)
    g3m_k<<<dim3(16, 64, 2), blk, 0, stream>>>(dbldt2, dtwT2, dtb_f, dtb_b, dltt2);
    // 6. scan (in-place over xct2) — structured-A dual loop
    scan8_k<<<dim3(4096), blk, 0, stream>>>(xct2, dltt2, dblt2,
                                            alog_f, alog_b, dp_f, dp_b);
    // 7. zgate: yrow2 = silu(x @ inw_z) * y  (writes over dead dltt2)
    zgate_k<<<dim3(8, 64, 2), blk, 0, stream>>>(xbf, inwT, xct2, yrow2);
    // 8. G4: mbf2[dir] = y @ out_w   M=4096 N=512 K=1024
    bgemm3_k<64, 0, false, false><<<dim3(8, 32, 2), blk, 0, stream>>>(
        yrow2, U, EDIM, outwT, (size_t)512 * 1024, EDIM, nullptr,
        mbf2, SZ_DM, DMODEL, nullptr, 0, nullptr, EDIM);
    // 9. LN on dir0 half of mbf2 (in place)
    ln_k<<<dim3(MROWS / 4), blk, 0, stream>>>(mbf2, n1g, n1b);
    // 10. G5: ffh2[dir] = relu(m @ fw1 + fb1)   M=4096 N=1024 K=512
    bgemm3_k<128, 2, false, false><<<dim3(8, 32, 2), blk, 0, stream>>>(
        mbf2, SZ_DM, DMODEL, fw1T, 0, DMODEL, fb1,
        ffh2, U, DFF, nullptr, 0, nullptr, DMODEL);
    // 11. G6 fused (concat-K): out = ffh_f@fw2 + ffh_b@fw2 + 2*fb2 + m_f + m_b
    bgemm3_k<64, 5, false, true><<<dim3(8, 32, 1), blk, 0, stream>>>(
        ffh2, U, DFF, fw2T, 0, DFF, fb2,
        nullptr, 0, DMODEL, mbf2, SZ_DM, out, 2 * DFF);
}